// Round 1
// baseline (1021.704 us; speedup 1.0000x reference)
//
#include <hip/hip_runtime.h>

#define CAP 128  // max in-degree slots per node (deg ~ Poisson(20), max ~50; 128 is >20 sigma)

__device__ __forceinline__ float sigf(float x) {
    return __builtin_amdgcn_rcpf(1.0f + __expf(-x));
}
__device__ __forceinline__ float tanhfast(float x) {
    return 2.0f * __builtin_amdgcn_rcpf(1.0f + __expf(-2.0f * x)) - 1.0f;
}

// ---------------- capped per-dst edge list build ----------------
__global__ void csr_fill_kernel(const int* __restrict__ dst, int* __restrict__ cnt,
                                int* __restrict__ eid, int E)
{
    int e = blockIdx.x * blockDim.x + threadIdx.x;
    if (e >= E) return;
    int d = dst[e];
    int k = atomicAdd(cnt + d, 1);
    if (k < CAP) eid[(size_t)d * CAP + k] = e;
}

// ---------------- edge LSTM: 64 edges/block, 128 gate-threads x 2 halves ----------------
// weights in VGPRs (32 each), h tile in LDS read uniform (broadcast, conflict-free)
__global__ __launch_bounds__(256) void edge_lstm_kernel(
    const float* __restrict__ eattr, const float* __restrict__ h_in,
    const float* __restrict__ c_in,
    const float* __restrict__ Wih, const float* __restrict__ Whh,
    const float* __restrict__ bih, const float* __restrict__ bhh,
    float* __restrict__ he_out, float* __restrict__ ce_out, int E)
{
    __shared__ float hbuf[64 * 32];
    __shared__ float eabuf[64 * 2];
    __shared__ float gbuf[64 * 128];
    const int tid = threadIdx.x;
    const int e0 = blockIdx.x * 64;
    const int ne = min(64, E - e0);
    {
        const float4* src = (const float4*)(h_in + (size_t)e0 * 32);
        float4* dst = (float4*)hbuf;
        for (int i = tid; i < ne * 8; i += 256) dst[i] = src[i];
        const float* es = eattr + (size_t)e0 * 2;
        for (int i = tid; i < ne * 2; i += 256) eabuf[i] = es[i];
    }
    const int G = tid & 127;          // gate row 0..127 (i,f,g,o x 32)
    float w[32];
    #pragma unroll
    for (int k4 = 0; k4 < 8; ++k4) {
        float4 v = ((const float4*)(Whh + G * 32))[k4];
        w[k4*4+0] = v.x; w[k4*4+1] = v.y; w[k4*4+2] = v.z; w[k4*4+3] = v.w;
    }
    const float wi0 = Wih[G*2], wi1 = Wih[G*2+1];
    const float bsum = bih[G] + bhh[G];
    __syncthreads();
    const int ebeg = (tid >> 7) * 32;
    const int eend = min(ebeg + 32, ne);
    for (int e = ebeg; e < eend; ++e) {
        float acc = bsum + wi0 * eabuf[e*2] + wi1 * eabuf[e*2+1];
        const float* hr = hbuf + e * 32;
        #pragma unroll
        for (int k = 0; k < 32; ++k) acc += w[k] * hr[k];
        gbuf[e * 128 + G] = acc;      // lane-consecutive G -> conflict-free
    }
    __syncthreads();
    const int nl = ne * 32;
    for (int r = 0; r < 8; ++r) {
        int l = r * 256 + tid;
        if (l >= nl) break;
        int e = l >> 5, j = l & 31;
        float gi = gbuf[e*128 + j];
        float gf = gbuf[e*128 + 32 + j];
        float gg = gbuf[e*128 + 64 + j];
        float go = gbuf[e*128 + 96 + j];
        float cold = c_in[(size_t)e0*32 + l];
        float c2 = sigf(gf) * cold + sigf(gi) * tanhfast(gg);
        float h2 = sigf(go) * tanhfast(c2);
        he_out[(size_t)e0*32 + l] = h2;
        ce_out[(size_t)e0*32 + l] = c2;
    }
}

// ---------------- node LSTM: 16 nodes/block, 512 gates x 2 K-halves ----------------
__global__ __launch_bounds__(1024, 1) void node_lstm_kernel(
    const float* __restrict__ x, const float* __restrict__ h_in, const float* __restrict__ c_in,
    const float* __restrict__ Wih, const float* __restrict__ Whh,
    const float* __restrict__ bih, const float* __restrict__ bhh,
    float* __restrict__ hn_out, float* __restrict__ cn_out, int N)
{
    __shared__ float hbuf[16 * 128];
    __shared__ float xbuf[16 * 8];
    __shared__ float gbuf[16 * 512];
    const int tid = threadIdx.x;
    const int n0 = blockIdx.x * 16;
    const int nn = min(16, N - n0);
    {
        const float4* src = (const float4*)(h_in + (size_t)n0 * 128);
        float4* dst = (float4*)hbuf;
        for (int i = tid; i < nn * 32; i += 1024) dst[i] = src[i];
        for (int i = tid; i < nn * 5; i += 1024) xbuf[(i/5)*8 + (i%5)] = x[(size_t)n0*5 + i];
    }
    const int G = tid >> 1, q = tid & 1;   // gate row 0..511, K-half
    float4 wv[16];
    #pragma unroll
    for (int k4 = 0; k4 < 16; ++k4) wv[k4] = ((const float4*)(Whh + (size_t)G*128 + q*64))[k4];
    float wih0=0,wih1=0,wih2=0,wih3=0,wih4=0, bsum=0;
    if (q == 0) {
        wih0 = Wih[G*5+0]; wih1 = Wih[G*5+1]; wih2 = Wih[G*5+2];
        wih3 = Wih[G*5+3]; wih4 = Wih[G*5+4];
        bsum = bih[G] + bhh[G];
    }
    __syncthreads();
    for (int n = 0; n < nn; ++n) {
        const float4* hr = (const float4*)(hbuf + n*128) + q*16;   // uniform addr -> broadcast
        float s = 0.f;
        #pragma unroll
        for (int k4 = 0; k4 < 16; ++k4) {
            float4 h4 = hr[k4];
            s += wv[k4].x*h4.x; s += wv[k4].y*h4.y; s += wv[k4].z*h4.z; s += wv[k4].w*h4.w;
        }
        float other = __shfl_xor(s, 1);
        if (q == 0) {
            float tot = s + other + bsum
                      + wih0*xbuf[n*8+0] + wih1*xbuf[n*8+1] + wih2*xbuf[n*8+2]
                      + wih3*xbuf[n*8+3] + wih4*xbuf[n*8+4];
            gbuf[n*512 + G] = tot;
        }
    }
    __syncthreads();
    const int nl = nn * 128;
    for (int r = 0; r < 2; ++r) {
        int l = r*1024 + tid;
        if (l >= nl) break;
        int n = l >> 7, j = l & 127;
        float gi = gbuf[n*512 + j];
        float gf = gbuf[n*512 + 128 + j];
        float gg = gbuf[n*512 + 256 + j];
        float go = gbuf[n*512 + 384 + j];
        float cold = c_in[(size_t)n0*128 + l];
        float c2 = sigf(gf)*cold + sigf(gi)*tanhfast(gg);
        float h2 = sigf(go)*tanhfast(c2);
        hn_out[(size_t)n0*128 + l] = h2;
        cn_out[(size_t)n0*128 + l] = c2;
    }
}

// ---------------- scatter-mean of he into edge_enc: one wave per node ----------------
__global__ __launch_bounds__(256) void edge_enc_kernel(
    const int* __restrict__ cnt, const int* __restrict__ eid,
    const float* __restrict__ he, float* __restrict__ enc, int N)
{
    const int wid = (blockIdx.x * blockDim.x + threadIdx.x) >> 6;
    const int lane = threadIdx.x & 63;
    if (wid >= N) return;
    const int c = cnt[wid];
    const int m = min(c, CAP);
    const int j = lane & 31, half = lane >> 5;
    const int* el = eid + (size_t)wid * CAP;
    float acc = 0.f;
    for (int i = half; i < m; i += 2)
        acc += he[(size_t)el[i]*32 + j];
    acc += __shfl_xor(acc, 32);
    if (lane < 32) enc[(size_t)wid*32 + lane] = acc / fmaxf((float)c, 1.0f);
}

// ---------------- xl = [hn, enc] @ W_gat  +  attention logits ----------------
__global__ __launch_bounds__(256) void gat_xl_kernel(
    const float* __restrict__ hn, const float* __restrict__ enc,
    const float* __restrict__ Wg, const float* __restrict__ attS, const float* __restrict__ attD,
    float* __restrict__ xl, float* __restrict__ asrc, float* __restrict__ adst, int N)
{
    __shared__ float Wbuf[160 * 64];
    __shared__ float fbuf[16 * 164];   // stride 164 breaks 160 % 32 == 0 bank alias
    __shared__ float xlbuf[16 * 64];
    const int tid = threadIdx.x;
    const int n0 = blockIdx.x * 16;
    const int nn = min(16, N - n0);
    {
        const float4* src = (const float4*)Wg;
        float4* dst = (float4*)Wbuf;
        for (int i = tid; i < 160 * 16; i += 256) dst[i] = src[i];
        const float4* hsrc = (const float4*)(hn + (size_t)n0 * 128);
        for (int i = tid; i < nn * 32; i += 256) {
            int n = i >> 5, k4 = i & 31;
            float4 v = hsrc[i];
            fbuf[n*164 + k4*4+0] = v.x; fbuf[n*164 + k4*4+1] = v.y;
            fbuf[n*164 + k4*4+2] = v.z; fbuf[n*164 + k4*4+3] = v.w;
        }
        const float* esrc = enc + (size_t)n0 * 32;
        for (int i = tid; i < nn * 32; i += 256) {
            int n = i >> 5, j = i & 31;
            fbuf[n*164 + 128 + j] = esrc[n*32 + j];
        }
    }
    __syncthreads();
    const int n = tid >> 4, hcq = tid & 15;
    if (n < nn) {
        float ax = 0.f, ay = 0.f, az = 0.f, aw = 0.f;
        const float* fr = fbuf + n * 164;
        #pragma unroll 4
        for (int k = 0; k < 160; ++k) {
            float f = fr[k];
            const float4 w4 = ((const float4*)(Wbuf + k*64))[hcq];
            ax += f*w4.x; ay += f*w4.y; az += f*w4.z; aw += f*w4.w;
        }
        float4 res; res.x = ax; res.y = ay; res.z = az; res.w = aw;
        ((float4*)(xl + (size_t)(n0+n)*64))[hcq] = res;
        ((float4*)(xlbuf + n*64))[hcq] = res;
    }
    __syncthreads();
    if (tid < nn * 4) {
        int n2 = tid >> 2, h = tid & 3;
        float s1 = 0.f, s2 = 0.f;
        #pragma unroll
        for (int c = 0; c < 16; ++c) {
            float v = xlbuf[n2*64 + h*16 + c];
            s1 += v * attS[h*16 + c];
            s2 += v * attD[h*16 + c];
        }
        asrc[(size_t)(n0+n2)*4 + h] = s1;
        adst[(size_t)(n0+n2)*4 + h] = s2;
    }
}

// ---------------- fused GAT softmax + aggregation: one wave per node ----------------
// lane = h*16+c; phase1: max over alphas (incl. self loop); phase2: exp/sum/weighted gather
__global__ __launch_bounds__(256) void gat_node_kernel(
    const int* __restrict__ cnt, const int* __restrict__ eid,
    const int* __restrict__ src_idx,
    const float* __restrict__ asrc, const float* __restrict__ adst,
    const float* __restrict__ xl, const float* __restrict__ bias,
    float* __restrict__ out, int N)
{
    const int wid = (blockIdx.x * blockDim.x + threadIdx.x) >> 6;
    const int lane = threadIdx.x & 63;
    if (wid >= N) return;
    const int n = wid;
    const int m = min(cnt[n], CAP);
    const int h = lane >> 4;
    const float ad = adst[n*4 + h];
    float aself = asrc[n*4 + h] + ad;
    aself = aself > 0.f ? aself : 0.2f * aself;
    float mx = aself;
    const int* el = eid + (size_t)n * CAP;
    for (int i = (lane & 15); i < m; i += 16) {          // each h-group covers all edges
        int s = src_idx[el[i]];
        float a = asrc[s*4 + h] + ad;
        a = a > 0.f ? a : 0.2f * a;
        mx = fmaxf(mx, a);
    }
    #pragma unroll
    for (int off = 1; off < 16; off <<= 1) mx = fmaxf(mx, __shfl_xor(mx, off));
    float sacc = __expf(aself - mx);                     // self loop
    float oacc = sacc * xl[(size_t)n*64 + lane];
    for (int i = 0; i < m; ++i) {                        // serial over edges, all 64 lanes
        int s = src_idx[el[i]];
        float a = asrc[s*4 + h] + ad;
        a = a > 0.f ? a : 0.2f * a;
        float ea = __expf(a - mx);
        sacc += ea;
        oacc += ea * xl[(size_t)s*64 + lane];            // one 256B row gather per wave
    }
    float r = oacc / sacc;
    r += __shfl_xor(r, 16);                              // sum over heads
    r += __shfl_xor(r, 32);
    if (lane < 16) out[(size_t)n*16 + lane] = 0.25f * r + bias[lane];
}

extern "C" void kernel_launch(void* const* d_in, const int* in_sizes, int n_in,
                              void* d_out, int out_size, void* d_ws, size_t ws_size,
                              hipStream_t stream)
{
    const float* x     = (const float*)d_in[0];
    const int*   ei    = (const int*)  d_in[1];
    const float* eattr = (const float*)d_in[2];
    const float* hn_h  = (const float*)d_in[3];
    const float* hn_c  = (const float*)d_in[4];
    const float* he_h  = (const float*)d_in[5];
    const float* he_c  = (const float*)d_in[6];
    const float* Wih_n = (const float*)d_in[7];
    const float* Whh_n = (const float*)d_in[8];
    const float* bih_n = (const float*)d_in[9];
    const float* bhh_n = (const float*)d_in[10];
    const float* Wih_e = (const float*)d_in[11];
    const float* Whh_e = (const float*)d_in[12];
    const float* bih_e = (const float*)d_in[13];
    const float* bhh_e = (const float*)d_in[14];
    const float* W_gat = (const float*)d_in[15];
    const float* attS  = (const float*)d_in[16];
    const float* attD  = (const float*)d_in[17];
    const float* biasG = (const float*)d_in[18];

    const int N = in_sizes[0] / 5;     // node count
    const int E = in_sizes[2] / 2;     // edge count

    float* out = (float*)d_out;
    float* hn  = out + (size_t)N * 16;
    float* cn  = hn  + (size_t)N * 128;
    float* he  = cn  + (size_t)N * 128;
    float* ce  = he  + (size_t)E * 32;

    char* p = (char*)d_ws;
    size_t off = 0;
    auto take = [&](size_t bytes) -> void* {
        void* r = p + off;
        off = (off + bytes + 255) & ~(size_t)255;
        return r;
    };
    int*   cnt  = (int*)  take((size_t)N * 4);
    int*   eid  = (int*)  take((size_t)N * CAP * 4);
    float* enc  = (float*)take((size_t)N * 32 * 4);
    float* xl   = (float*)take((size_t)N * 64 * 4);
    float* asrc = (float*)take((size_t)N * 4 * 4);
    float* adst = (float*)take((size_t)N * 4 * 4);

    hipMemsetAsync(cnt, 0, (size_t)N * 4, stream);
    csr_fill_kernel<<<(E + 255)/256, 256, 0, stream>>>(ei + E, cnt, eid, E);
    edge_lstm_kernel<<<(E + 63)/64, 256, 0, stream>>>(
        eattr, he_h, he_c, Wih_e, Whh_e, bih_e, bhh_e, he, ce, E);
    node_lstm_kernel<<<(N + 15)/16, 1024, 0, stream>>>(
        x, hn_h, hn_c, Wih_n, Whh_n, bih_n, bhh_n, hn, cn, N);
    edge_enc_kernel<<<(N + 3)/4, 256, 0, stream>>>(cnt, eid, he, enc, N);
    gat_xl_kernel<<<(N + 15)/16, 256, 0, stream>>>(
        hn, enc, W_gat, attS, attD, xl, asrc, adst, N);
    gat_node_kernel<<<(N + 3)/4, 256, 0, stream>>>(
        cnt, eid, ei, asrc, adst, xl, biasG, out, N);
}

// Round 2
// 600.786 us; speedup vs baseline: 1.7006x; 1.7006x over previous
//
#include <hip/hip_runtime.h>

#define CAP 128  // max in-degree slots per node

typedef __attribute__((ext_vector_type(8))) short bf16x8;
typedef __attribute__((ext_vector_type(4))) float f32x4;

__device__ __forceinline__ float sigf(float x) {
    return __builtin_amdgcn_rcpf(1.0f + __expf(-x));
}
__device__ __forceinline__ float tanhfast(float x) {
    return 2.0f * __builtin_amdgcn_rcpf(1.0f + __expf(-2.0f * x)) - 1.0f;
}
__device__ __forceinline__ short bfr(float f) {          // fp32 -> bf16 RNE
    unsigned u = __float_as_uint(f);
    unsigned r = (u + 0x7FFFu + ((u >> 16) & 1u)) >> 16;
    return (short)r;
}
__device__ __forceinline__ bf16x8 cvt8(const float* p) { // 8 contiguous fp32 -> bf16x8
    const float4* q = (const float4*)p;
    float4 u = q[0], v = q[1];
    bf16x8 r;
    r[0]=bfr(u.x); r[1]=bfr(u.y); r[2]=bfr(u.z); r[3]=bfr(u.w);
    r[4]=bfr(v.x); r[5]=bfr(v.y); r[6]=bfr(v.z); r[7]=bfr(v.w);
    return r;
}

// ---------------- weight conversion / packing (tiny, once per launch) ----------------
// Wn [512][160] = [Whh_n (128) | Wih_n (5) | zeros]; We [128][64] = [Whh_e (32) | Wih_e (2) | zeros]
// Wgt [64][160] = W_gat^T; bsn = bih_n+bhh_n; bse = bih_e+bhh_e
__global__ void convert_kernel(
    const float* __restrict__ Whh_n, const float* __restrict__ Wih_n,
    const float* __restrict__ bih_n, const float* __restrict__ bhh_n,
    const float* __restrict__ Whh_e, const float* __restrict__ Wih_e,
    const float* __restrict__ bih_e, const float* __restrict__ bhh_e,
    const float* __restrict__ Wgat,
    unsigned short* __restrict__ Wn, unsigned short* __restrict__ We,
    unsigned short* __restrict__ Wgt, float* __restrict__ bsn, float* __restrict__ bse)
{
    int i = blockIdx.x * 256 + threadIdx.x;
    if (i < 512 * 160) {
        int g = i / 160, k = i % 160;
        float v = (k < 128) ? Whh_n[g * 128 + k] : (k < 133 ? Wih_n[g * 5 + (k - 128)] : 0.f);
        Wn[i] = (unsigned short)bfr(v);
    }
    if (i < 128 * 64) {
        int g = i / 64, k = i % 64;
        float v = (k < 32) ? Whh_e[g * 32 + k] : (k < 34 ? Wih_e[g * 2 + (k - 32)] : 0.f);
        We[i] = (unsigned short)bfr(v);
    }
    if (i < 64 * 160) {
        int c = i / 160, k = i % 160;
        Wgt[i] = (unsigned short)bfr(Wgat[k * 64 + c]);
    }
    if (i < 512) bsn[i] = bih_n[i] + bhh_n[i];
    if (i < 128) bse[i] = bih_e[i] + bhh_e[i];
}

// ---------------- capped per-dst edge list build ----------------
__global__ void csr_fill_kernel(const int* __restrict__ dst, int* __restrict__ cnt,
                                int* __restrict__ eid, int E)
{
    int e = blockIdx.x * blockDim.x + threadIdx.x;
    if (e >= E) return;
    int d = dst[e];
    int k = atomicAdd(cnt + d, 1);
    if (k < CAP) eid[(size_t)d * CAP + k] = e;
}

// ---------------- node LSTM via MFMA: wave = 16 nodes x 512 gates, K=160 ----------------
__global__ __launch_bounds__(256) void node_lstm_mfma(
    const float* __restrict__ x, const float* __restrict__ h_in, const float* __restrict__ c_in,
    const unsigned short* __restrict__ Wn, const float* __restrict__ bsn,
    float* __restrict__ hn_out, float* __restrict__ cn_out, int N)
{
    const int lane = threadIdx.x & 63, wave = threadIdx.x >> 6;
    const int n0 = blockIdx.x * 64 + wave * 16;
    if (n0 >= N) return;                         // N % 16 == 0
    const int lr = lane & 15, lg = lane >> 4;
    const int arow = n0 + lr;
    // A fragments: lane holds A[row=lr][k=lg*8+j]; k4 steps of 32
    bf16x8 a[5];
    const float* hp = h_in + (size_t)arow * 128 + lg * 8;
    a[0] = cvt8(hp); a[1] = cvt8(hp + 32); a[2] = cvt8(hp + 64); a[3] = cvt8(hp + 96);
    bf16x8 ax = {0,0,0,0,0,0,0,0};
    if (lg == 0) {                               // K-ext: k 128..132 = x[row][0..4]
        const float* xp = x + (size_t)arow * 5;
        ax[0]=bfr(xp[0]); ax[1]=bfr(xp[1]); ax[2]=bfr(xp[2]); ax[3]=bfr(xp[3]); ax[4]=bfr(xp[4]);
    }
    a[4] = ax;
    const bf16x8* Wv = (const bf16x8*)Wn;        // row stride 160/8 = 20 units
    #pragma unroll
    for (int jb = 0; jb < 8; ++jb) {             // j-block: gates {jb*16+lr} for i,f,g,o
        const bf16x8* bp = Wv + (size_t)(jb * 16 + lr) * 20 + lg;
        f32x4 vi = {0,0,0,0}, vf = {0,0,0,0}, vg = {0,0,0,0}, vo = {0,0,0,0};
        #pragma unroll
        for (int k4 = 0; k4 < 5; ++k4) {
            vi = __builtin_amdgcn_mfma_f32_16x16x32_bf16(a[k4], bp[k4*4],        vi, 0, 0, 0);
            vf = __builtin_amdgcn_mfma_f32_16x16x32_bf16(a[k4], bp[k4*4 + 2560], vf, 0, 0, 0);
            vg = __builtin_amdgcn_mfma_f32_16x16x32_bf16(a[k4], bp[k4*4 + 5120], vg, 0, 0, 0);
            vo = __builtin_amdgcn_mfma_f32_16x16x32_bf16(a[k4], bp[k4*4 + 7680], vo, 0, 0, 0);
        }
        // D layout: col = lane&15 (=lr), row = lg*4 + q
        const int j = jb * 16 + lr;
        const float bi = bsn[j], bf_ = bsn[128 + j], bg_ = bsn[256 + j], bo_ = bsn[384 + j];
        #pragma unroll
        for (int q = 0; q < 4; ++q) {
            const int node = n0 + lg * 4 + q;
            float gi = vi[q] + bi, gf = vf[q] + bf_, gg = vg[q] + bg_, go = vo[q] + bo_;
            float cold = c_in[(size_t)node * 128 + j];
            float c2 = sigf(gf) * cold + sigf(gi) * tanhfast(gg);
            float h2 = sigf(go) * tanhfast(c2);
            cn_out[(size_t)node * 128 + j] = c2;
            hn_out[(size_t)node * 128 + j] = h2;
        }
    }
}

// ---------------- edge LSTM via MFMA: wave = 16 edges x 128 gates, K=64 (32+2 ext) ----------------
__global__ __launch_bounds__(256) void edge_lstm_mfma(
    const float* __restrict__ eattr, const float* __restrict__ h_in, const float* __restrict__ c_in,
    const unsigned short* __restrict__ We, const float* __restrict__ bse,
    float* __restrict__ he_out, float* __restrict__ ce_out, int E)
{
    const int lane = threadIdx.x & 63, wave = threadIdx.x >> 6;
    const int e0 = blockIdx.x * 64 + wave * 16;
    if (e0 >= E) return;                         // E % 16 == 0
    const int lr = lane & 15, lg = lane >> 4;
    const int arow = e0 + lr;
    bf16x8 a0 = cvt8(h_in + (size_t)arow * 32 + lg * 8);
    bf16x8 a1 = {0,0,0,0,0,0,0,0};
    if (lg == 0) { a1[0] = bfr(eattr[(size_t)arow * 2]); a1[1] = bfr(eattr[(size_t)arow * 2 + 1]); }
    const bf16x8* Wv = (const bf16x8*)We;        // row stride 64/8 = 8 units
    f32x4 acc[8];
    #pragma unroll
    for (int t = 0; t < 8; ++t) {
        const bf16x8* bp = Wv + (size_t)(t * 16 + lr) * 8 + lg;
        f32x4 v = {0,0,0,0};
        v = __builtin_amdgcn_mfma_f32_16x16x32_bf16(a0, bp[0], v, 0, 0, 0);
        v = __builtin_amdgcn_mfma_f32_16x16x32_bf16(a1, bp[4], v, 0, 0, 0);
        acc[t] = v;
    }
    #pragma unroll
    for (int u = 0; u < 2; ++u) {                // j = u*16+lr in 0..31
        const int j = u * 16 + lr;
        const float bi = bse[j], bf_ = bse[32 + j], bg_ = bse[64 + j], bo_ = bse[96 + j];
        #pragma unroll
        for (int q = 0; q < 4; ++q) {
            const int row = e0 + lg * 4 + q;
            float gi = acc[u][q] + bi, gf = acc[u+2][q] + bf_;
            float gg = acc[u+4][q] + bg_, go = acc[u+6][q] + bo_;
            float cold = c_in[(size_t)row * 32 + j];
            float c2 = sigf(gf) * cold + sigf(gi) * tanhfast(gg);
            float h2 = sigf(go) * tanhfast(c2);
            ce_out[(size_t)row * 32 + j] = c2;
            he_out[(size_t)row * 32 + j] = h2;
        }
    }
}

// ---------------- scatter-mean of he into edge_enc: one wave per node ----------------
__global__ __launch_bounds__(256) void edge_enc_kernel(
    const int* __restrict__ cnt, const int* __restrict__ eid,
    const float* __restrict__ he, float* __restrict__ enc, int N)
{
    const int wid = (blockIdx.x * blockDim.x + threadIdx.x) >> 6;
    const int lane = threadIdx.x & 63;
    if (wid >= N) return;
    const int c = cnt[wid];
    const int m = min(c, CAP);
    const int j = lane & 31, half = lane >> 5;
    const int* el = eid + (size_t)wid * CAP;
    float acc = 0.f;
    for (int i = half; i < m; i += 2)
        acc += he[(size_t)el[i] * 32 + j];
    acc += __shfl_xor(acc, 32);
    if (lane < 32) enc[(size_t)wid * 32 + lane] = acc / fmaxf((float)c, 1.0f);
}

// ---------------- GAT linear via MFMA: wave = 16 nodes x 64 cols, K=160 ----------------
// also computes attention logits via 4-bit butterfly reduce (head = tile index)
__global__ __launch_bounds__(256) void gat_xl_mfma(
    const float* __restrict__ hn, const float* __restrict__ enc,
    const unsigned short* __restrict__ Wgt,
    const float* __restrict__ attS, const float* __restrict__ attD,
    float* __restrict__ xl, float* __restrict__ asrc, float* __restrict__ adst, int N)
{
    const int lane = threadIdx.x & 63, wave = threadIdx.x >> 6;
    const int n0 = blockIdx.x * 64 + wave * 16;
    if (n0 >= N) return;
    const int lr = lane & 15, lg = lane >> 4;
    const int arow = n0 + lr;
    bf16x8 a[5];
    const float* hp = hn + (size_t)arow * 128 + lg * 8;
    a[0] = cvt8(hp); a[1] = cvt8(hp + 32); a[2] = cvt8(hp + 64); a[3] = cvt8(hp + 96);
    a[4] = cvt8(enc + (size_t)arow * 32 + lg * 8);          // K 128..159 = enc
    const bf16x8* Wv = (const bf16x8*)Wgt;                   // row stride 20 units
    #pragma unroll
    for (int t = 0; t < 4; ++t) {                            // t = head
        const bf16x8* bp = Wv + (size_t)(t * 16 + lr) * 20 + lg;
        f32x4 v = {0,0,0,0};
        #pragma unroll
        for (int k4 = 0; k4 < 5; ++k4)
            v = __builtin_amdgcn_mfma_f32_16x16x32_bf16(a[k4], bp[k4*4], v, 0, 0, 0);
        const float ws = attS[t * 16 + lr], wd = attD[t * 16 + lr];
        #pragma unroll
        for (int q = 0; q < 4; ++q) {
            const int node = n0 + lg * 4 + q;
            const float val = v[q];
            xl[(size_t)node * 64 + t * 16 + lr] = val;
            float p1 = val * ws, p2 = val * wd;
            #pragma unroll
            for (int off = 1; off < 16; off <<= 1) {
                p1 += __shfl_xor(p1, off);
                p2 += __shfl_xor(p2, off);
            }
            if (lr == 0) {
                asrc[(size_t)node * 4 + t] = p1;
                adst[(size_t)node * 4 + t] = p2;
            }
        }
    }
}

// ---------------- fused GAT softmax + aggregation: one wave per node ----------------
__global__ __launch_bounds__(256) void gat_node_kernel(
    const int* __restrict__ cnt, const int* __restrict__ eid,
    const int* __restrict__ src_idx,
    const float* __restrict__ asrc, const float* __restrict__ adst,
    const float* __restrict__ xl, const float* __restrict__ bias,
    float* __restrict__ out, int N)
{
    const int wid = (blockIdx.x * blockDim.x + threadIdx.x) >> 6;
    const int lane = threadIdx.x & 63;
    if (wid >= N) return;
    const int n = wid;
    const int m = min(cnt[n], CAP);
    const int h = lane >> 4;
    const float ad = adst[n * 4 + h];
    float aself = asrc[n * 4 + h] + ad;
    aself = aself > 0.f ? aself : 0.2f * aself;
    float mx = aself;
    const int* el = eid + (size_t)n * CAP;
    for (int i = (lane & 15); i < m; i += 16) {
        int s = src_idx[el[i]];
        float a = asrc[s * 4 + h] + ad;
        a = a > 0.f ? a : 0.2f * a;
        mx = fmaxf(mx, a);
    }
    #pragma unroll
    for (int off = 1; off < 16; off <<= 1) mx = fmaxf(mx, __shfl_xor(mx, off));
    float sacc = __expf(aself - mx);
    float oacc = sacc * xl[(size_t)n * 64 + lane];
    for (int i = 0; i < m; ++i) {
        int s = src_idx[el[i]];
        float a = asrc[s * 4 + h] + ad;
        a = a > 0.f ? a : 0.2f * a;
        float ea = __expf(a - mx);
        sacc += ea;
        oacc += ea * xl[(size_t)s * 64 + lane];
    }
    float r = oacc / sacc;
    r += __shfl_xor(r, 16);
    r += __shfl_xor(r, 32);
    if (lane < 16) out[(size_t)n * 16 + lane] = 0.25f * r + bias[lane];
}

extern "C" void kernel_launch(void* const* d_in, const int* in_sizes, int n_in,
                              void* d_out, int out_size, void* d_ws, size_t ws_size,
                              hipStream_t stream)
{
    const float* x     = (const float*)d_in[0];
    const int*   ei    = (const int*)  d_in[1];
    const float* eattr = (const float*)d_in[2];
    const float* hn_h  = (const float*)d_in[3];
    const float* hn_c  = (const float*)d_in[4];
    const float* he_h  = (const float*)d_in[5];
    const float* he_c  = (const float*)d_in[6];
    const float* Wih_n = (const float*)d_in[7];
    const float* Whh_n = (const float*)d_in[8];
    const float* bih_n = (const float*)d_in[9];
    const float* bhh_n = (const float*)d_in[10];
    const float* Wih_e = (const float*)d_in[11];
    const float* Whh_e = (const float*)d_in[12];
    const float* bih_e = (const float*)d_in[13];
    const float* bhh_e = (const float*)d_in[14];
    const float* W_gat = (const float*)d_in[15];
    const float* attS  = (const float*)d_in[16];
    const float* attD  = (const float*)d_in[17];
    const float* biasG = (const float*)d_in[18];

    const int N = in_sizes[0] / 5;
    const int E = in_sizes[2] / 2;

    float* out = (float*)d_out;
    float* hn  = out + (size_t)N * 16;
    float* cn  = hn  + (size_t)N * 128;
    float* he  = cn  + (size_t)N * 128;
    float* ce  = he  + (size_t)E * 32;

    char* p = (char*)d_ws;
    size_t off = 0;
    auto take = [&](size_t bytes) -> void* {
        void* r = p + off;
        off = (off + bytes + 255) & ~(size_t)255;
        return r;
    };
    int*   cnt  = (int*)  take((size_t)N * 4);
    int*   eid  = (int*)  take((size_t)N * CAP * 4);
    float* enc  = (float*)take((size_t)N * 32 * 4);
    float* xl   = (float*)take((size_t)N * 64 * 4);
    float* asrc = (float*)take((size_t)N * 4 * 4);
    float* adst = (float*)take((size_t)N * 4 * 4);
    unsigned short* Wn  = (unsigned short*)take(512 * 160 * 2);
    unsigned short* We  = (unsigned short*)take(128 * 64 * 2);
    unsigned short* Wgt = (unsigned short*)take(64 * 160 * 2);
    float* bsn = (float*)take(512 * 4);
    float* bse = (float*)take(128 * 4);

    hipMemsetAsync(cnt, 0, (size_t)N * 4, stream);
    convert_kernel<<<(512 * 160 + 255) / 256, 256, 0, stream>>>(
        Whh_n, Wih_n, bih_n, bhh_n, Whh_e, Wih_e, bih_e, bhh_e, W_gat,
        Wn, We, Wgt, bsn, bse);
    csr_fill_kernel<<<(E + 255) / 256, 256, 0, stream>>>(ei + E, cnt, eid, E);
    edge_lstm_mfma<<<(E + 63) / 64, 256, 0, stream>>>(
        eattr, he_h, he_c, We, bse, he, ce, E);
    node_lstm_mfma<<<(N + 63) / 64, 256, 0, stream>>>(
        x, hn_h, hn_c, Wn, bsn, hn, cn, N);
    edge_enc_kernel<<<(N + 3) / 4, 256, 0, stream>>>(cnt, eid, he, enc, N);
    gat_xl_mfma<<<(N + 63) / 64, 256, 0, stream>>>(
        hn, enc, Wgt, attS, attD, xl, asrc, adst, N);
    gat_node_kernel<<<(N + 3) / 4, 256, 0, stream>>>(
        cnt, eid, ei, asrc, adst, xl, biasG, out, N);
}

// Round 3
// 504.748 us; speedup vs baseline: 2.0242x; 1.1903x over previous
//
#include <hip/hip_runtime.h>

#define CAP 128  // max in-degree slots per node

typedef __attribute__((ext_vector_type(8))) short bf16x8;
typedef __attribute__((ext_vector_type(4))) float f32x4;

__device__ __forceinline__ float sigf(float x) {
    return __builtin_amdgcn_rcpf(1.0f + __expf(-x));
}
__device__ __forceinline__ float tanhfast(float x) {
    return 2.0f * __builtin_amdgcn_rcpf(1.0f + __expf(-2.0f * x)) - 1.0f;
}
__device__ __forceinline__ short bfr(float f) {          // fp32 -> bf16 RNE
    unsigned u = __float_as_uint(f);
    unsigned r = (u + 0x7FFFu + ((u >> 16) & 1u)) >> 16;
    return (short)r;
}
__device__ __forceinline__ bf16x8 cvt8(const float* p) { // 8 contiguous fp32 -> bf16x8
    const float4* q = (const float4*)p;
    float4 u = q[0], v = q[1];
    bf16x8 r;
    r[0]=bfr(u.x); r[1]=bfr(u.y); r[2]=bfr(u.z); r[3]=bfr(u.w);
    r[4]=bfr(v.x); r[5]=bfr(v.y); r[6]=bfr(v.z); r[7]=bfr(v.w);
    return r;
}

// ---------------- weight conversion / packing (tiny, once per launch) ----------------
__global__ void convert_kernel(
    const float* __restrict__ Whh_n, const float* __restrict__ Wih_n,
    const float* __restrict__ bih_n, const float* __restrict__ bhh_n,
    const float* __restrict__ Whh_e, const float* __restrict__ Wih_e,
    const float* __restrict__ bih_e, const float* __restrict__ bhh_e,
    const float* __restrict__ Wgat,
    unsigned short* __restrict__ Wn, unsigned short* __restrict__ We,
    unsigned short* __restrict__ Wgt, float* __restrict__ bsn, float* __restrict__ bse)
{
    int i = blockIdx.x * 256 + threadIdx.x;
    if (i < 512 * 160) {
        int g = i / 160, k = i % 160;
        float v = (k < 128) ? Whh_n[g * 128 + k] : (k < 133 ? Wih_n[g * 5 + (k - 128)] : 0.f);
        Wn[i] = (unsigned short)bfr(v);
    }
    if (i < 128 * 64) {
        int g = i / 64, k = i % 64;
        float v = (k < 32) ? Whh_e[g * 32 + k] : (k < 34 ? Wih_e[g * 2 + (k - 32)] : 0.f);
        We[i] = (unsigned short)bfr(v);
    }
    if (i < 64 * 160) {
        int c = i / 160, k = i % 160;
        Wgt[i] = (unsigned short)bfr(Wgat[k * 64 + c]);
    }
    if (i < 512) bsn[i] = bih_n[i] + bhh_n[i];
    if (i < 128) bse[i] = bih_e[i] + bhh_e[i];
}

// ---------------- capped per-dst edge list build ----------------
__global__ void csr_fill_kernel(const int* __restrict__ dst, int* __restrict__ cnt,
                                int* __restrict__ eid, int E)
{
    int e = blockIdx.x * blockDim.x + threadIdx.x;
    if (e >= E) return;
    int d = dst[e];
    int k = atomicAdd(cnt + d, 1);
    if (k < CAP) eid[(size_t)d * CAP + k] = e;
}

// ---------------- edge LSTM via MFMA (swapped operands: D[gate][edge]) ----------------
// wave = 4 tiles x 16 edges; lane owns edge (lane&15) x 4 consecutive gate cols -> float4 epilogue
__global__ __launch_bounds__(256) void edge_lstm_mfma(
    const float* __restrict__ eattr, const float* __restrict__ h_in, const float* __restrict__ c_in,
    const unsigned short* __restrict__ We, const float* __restrict__ bse,
    float* __restrict__ he_out, float* __restrict__ ce_out, int E)
{
    const int lane = threadIdx.x & 63, wave = threadIdx.x >> 6;
    const int lr = lane & 15, lg = lane >> 4;
    const bf16x8* Wv = (const bf16x8*)We;        // row stride 64 bf16 = 8 units
    // A-frags (weights): lane holds W[gate = t*16+lr][k = lg*8+j]; preload all 8 tiles x 2 K-steps
    bf16x8 wa0[8], wa1[8];
    #pragma unroll
    for (int t = 0; t < 8; ++t) {
        const bf16x8* bp = Wv + (size_t)(t * 16 + lr) * 8 + lg;
        wa0[t] = bp[0];
        wa1[t] = bp[4];
    }
    // per-lane bias vectors (gates jb..jb+3), invariant across tiles
    const int jb0 = lg * 4, jb1 = 16 + lg * 4;
    const f32x4 bi0 = *(const f32x4*)(bse + jb0),       bi1 = *(const f32x4*)(bse + jb1);
    const f32x4 bf0 = *(const f32x4*)(bse + 32 + jb0),  bf1 = *(const f32x4*)(bse + 32 + jb1);
    const f32x4 bg0 = *(const f32x4*)(bse + 64 + jb0),  bg1 = *(const f32x4*)(bse + 64 + jb1);
    const f32x4 bo0 = *(const f32x4*)(bse + 96 + jb0),  bo1 = *(const f32x4*)(bse + 96 + jb1);
    const int base = blockIdx.x * 256 + wave * 64;
    #pragma unroll
    for (int tile = 0; tile < 4; ++tile) {
        const int e0 = base + tile * 16;
        if (e0 >= E) break;                      // E % 16 == 0 -> full tiles
        const int edge = e0 + lr;
        bf16x8 b0 = cvt8(h_in + (size_t)edge * 32 + lg * 8);   // B: col=edge, k=lg*8+j
        bf16x8 b1 = {0,0,0,0,0,0,0,0};
        if (lg == 0) {
            b1[0] = bfr(eattr[(size_t)edge * 2]);
            b1[1] = bfr(eattr[(size_t)edge * 2 + 1]);
        }
        f32x4 acc[8];
        #pragma unroll
        for (int t = 0; t < 8; ++t) {
            f32x4 v = {0, 0, 0, 0};
            v = __builtin_amdgcn_mfma_f32_16x16x32_bf16(wa0[t], b0, v, 0, 0, 0);
            v = __builtin_amdgcn_mfma_f32_16x16x32_bf16(wa1[t], b1, v, 0, 0, 0);
            acc[t] = v;
        }
        // epilogue: lane owns edge, gate cols {u*16+lg*4 .. +3}
        #pragma unroll
        for (int u = 0; u < 2; ++u) {
            const int jb = u * 16 + lg * 4;
            const f32x4 bi = u ? bi1 : bi0, bf_ = u ? bf1 : bf0;
            const f32x4 bg_ = u ? bg1 : bg0, bo_ = u ? bo1 : bo0;
            f32x4 cold = *(const f32x4*)(c_in + (size_t)edge * 32 + jb);
            f32x4 cres, hres;
            #pragma unroll
            for (int q = 0; q < 4; ++q) {
                float gi = acc[u][q] + bi[q],     gf = acc[u + 2][q] + bf_[q];
                float gg = acc[u + 4][q] + bg_[q], go = acc[u + 6][q] + bo_[q];
                float c2 = sigf(gf) * cold[q] + sigf(gi) * tanhfast(gg);
                cres[q] = c2;
                hres[q] = sigf(go) * tanhfast(c2);
            }
            *(f32x4*)(ce_out + (size_t)edge * 32 + jb) = cres;
            *(f32x4*)(he_out + (size_t)edge * 32 + jb) = hres;
        }
    }
}

// ---------------- node LSTM via MFMA (swapped): wave = 16 nodes x 512 gates, K=160 ----------------
__global__ __launch_bounds__(256) void node_lstm_mfma(
    const float* __restrict__ x, const float* __restrict__ h_in, const float* __restrict__ c_in,
    const unsigned short* __restrict__ Wn, const float* __restrict__ bsn,
    float* __restrict__ hn_out, float* __restrict__ cn_out, int N)
{
    const int lane = threadIdx.x & 63, wave = threadIdx.x >> 6;
    const int n0 = blockIdx.x * 64 + wave * 16;
    if (n0 >= N) return;                         // N % 16 == 0
    const int lr = lane & 15, lg = lane >> 4;
    const int node = n0 + lr;
    bf16x8 b[5];
    const float* hp = h_in + (size_t)node * 128 + lg * 8;
    b[0] = cvt8(hp); b[1] = cvt8(hp + 32); b[2] = cvt8(hp + 64); b[3] = cvt8(hp + 96);
    bf16x8 bx = {0,0,0,0,0,0,0,0};
    if (lg == 0) {
        const float* xp = x + (size_t)node * 5;
        bx[0]=bfr(xp[0]); bx[1]=bfr(xp[1]); bx[2]=bfr(xp[2]); bx[3]=bfr(xp[3]); bx[4]=bfr(xp[4]);
    }
    b[4] = bx;
    const bf16x8* Wv = (const bf16x8*)Wn;        // row stride 160 bf16 = 20 units
    f32x4 acc[32];
    #pragma unroll
    for (int t = 0; t < 32; ++t) {
        const bf16x8* ap = Wv + (size_t)(t * 16 + lr) * 20 + lg;
        f32x4 v = {0, 0, 0, 0};
        #pragma unroll
        for (int k4 = 0; k4 < 5; ++k4)
            v = __builtin_amdgcn_mfma_f32_16x16x32_bf16(ap[k4 * 4], b[k4], v, 0, 0, 0);
        acc[t] = v;
    }
    // epilogue: lane owns node, cols {u*16+lg*4 .. +3}, u = 0..7
    #pragma unroll
    for (int u = 0; u < 8; ++u) {
        const int jb = u * 16 + lg * 4;
        f32x4 bi  = *(const f32x4*)(bsn + jb);
        f32x4 bf_ = *(const f32x4*)(bsn + 128 + jb);
        f32x4 bg_ = *(const f32x4*)(bsn + 256 + jb);
        f32x4 bo_ = *(const f32x4*)(bsn + 384 + jb);
        f32x4 cold = *(const f32x4*)(c_in + (size_t)node * 128 + jb);
        f32x4 cres, hres;
        #pragma unroll
        for (int q = 0; q < 4; ++q) {
            float gi = acc[u][q] + bi[q],       gf = acc[u + 8][q] + bf_[q];
            float gg = acc[u + 16][q] + bg_[q], go = acc[u + 24][q] + bo_[q];
            float c2 = sigf(gf) * cold[q] + sigf(gi) * tanhfast(gg);
            cres[q] = c2;
            hres[q] = sigf(go) * tanhfast(c2);
        }
        *(f32x4*)(cn_out + (size_t)node * 128 + jb) = cres;
        *(f32x4*)(hn_out + (size_t)node * 128 + jb) = hres;
    }
}

// ---------------- scatter-mean of he into edge_enc: one wave per node, 4-way ----------------
__global__ __launch_bounds__(256) void edge_enc_kernel(
    const int* __restrict__ cnt, const int* __restrict__ eid,
    const float* __restrict__ he, float* __restrict__ enc, int N)
{
    const int wid = (blockIdx.x * blockDim.x + threadIdx.x) >> 6;
    const int lane = threadIdx.x & 63;
    if (wid >= N) return;
    const int c = cnt[wid];
    const int m = min(c, CAP);
    const int quarter = lane >> 4, jj = (lane & 15) * 2;
    const int* el = eid + (size_t)wid * CAP;
    float a0 = 0.f, a1 = 0.f;
    for (int i = quarter; i < m; i += 4) {
        const float* r = he + (size_t)el[i] * 32 + jj;
        a0 += r[0]; a1 += r[1];
    }
    a0 += __shfl_xor(a0, 16); a1 += __shfl_xor(a1, 16);
    a0 += __shfl_xor(a0, 32); a1 += __shfl_xor(a1, 32);
    if (lane < 16) {
        float inv = 1.0f / fmaxf((float)c, 1.0f);
        enc[(size_t)wid * 32 + jj]     = a0 * inv;
        enc[(size_t)wid * 32 + jj + 1] = a1 * inv;
    }
}

// ---------------- GAT linear via MFMA (swapped): wave = 16 nodes x 64 cols, K=160 ----------------
__global__ __launch_bounds__(256) void gat_xl_mfma(
    const float* __restrict__ hn, const float* __restrict__ enc,
    const unsigned short* __restrict__ Wgt,
    const float* __restrict__ attS, const float* __restrict__ attD,
    float* __restrict__ xl, float* __restrict__ asrc, float* __restrict__ adst, int N)
{
    const int lane = threadIdx.x & 63, wave = threadIdx.x >> 6;
    const int n0 = blockIdx.x * 64 + wave * 16;
    if (n0 >= N) return;
    const int lr = lane & 15, lg = lane >> 4;
    const int node = n0 + lr;
    bf16x8 b[5];
    const float* hp = hn + (size_t)node * 128 + lg * 8;
    b[0] = cvt8(hp); b[1] = cvt8(hp + 32); b[2] = cvt8(hp + 64); b[3] = cvt8(hp + 96);
    b[4] = cvt8(enc + (size_t)node * 32 + lg * 8);
    const bf16x8* Wv = (const bf16x8*)Wgt;       // row stride 20 units
    #pragma unroll
    for (int t = 0; t < 4; ++t) {                // t = head; lane cols c = lg*4+q
        const bf16x8* ap = Wv + (size_t)(t * 16 + lr) * 20 + lg;
        f32x4 v = {0, 0, 0, 0};
        #pragma unroll
        for (int k4 = 0; k4 < 5; ++k4)
            v = __builtin_amdgcn_mfma_f32_16x16x32_bf16(ap[k4 * 4], b[k4], v, 0, 0, 0);
        *(f32x4*)(xl + (size_t)node * 64 + t * 16 + lg * 4) = v;
        const f32x4 ws = *(const f32x4*)(attS + t * 16 + lg * 4);
        const f32x4 wd = *(const f32x4*)(attD + t * 16 + lg * 4);
        float p1 = v[0]*ws[0] + v[1]*ws[1] + v[2]*ws[2] + v[3]*ws[3];
        float p2 = v[0]*wd[0] + v[1]*wd[1] + v[2]*wd[2] + v[3]*wd[3];
        p1 += __shfl_xor(p1, 16); p2 += __shfl_xor(p2, 16);
        p1 += __shfl_xor(p1, 32); p2 += __shfl_xor(p2, 32);
        if (lg == 0) {
            asrc[(size_t)node * 4 + t] = p1;
            adst[(size_t)node * 4 + t] = p2;
        }
    }
}

// ---------------- fused GAT softmax + aggregation: one wave per node ----------------
__global__ __launch_bounds__(256) void gat_node_kernel(
    const int* __restrict__ cnt, const int* __restrict__ eid,
    const int* __restrict__ src_idx,
    const float* __restrict__ asrc, const float* __restrict__ adst,
    const float* __restrict__ xl, const float* __restrict__ bias,
    float* __restrict__ out, int N)
{
    const int wid = (blockIdx.x * blockDim.x + threadIdx.x) >> 6;
    const int lane = threadIdx.x & 63;
    if (wid >= N) return;
    const int n = wid;
    const int m = min(cnt[n], CAP);
    const int h = lane >> 4;
    const float ad = adst[n * 4 + h];
    float aself = asrc[n * 4 + h] + ad;
    aself = aself > 0.f ? aself : 0.2f * aself;
    float mx = aself;
    const int* el = eid + (size_t)n * CAP;
    for (int i = (lane & 15); i < m; i += 16) {
        int s = src_idx[el[i]];
        float a = asrc[s * 4 + h] + ad;
        a = a > 0.f ? a : 0.2f * a;
        mx = fmaxf(mx, a);
    }
    #pragma unroll
    for (int off = 1; off < 16; off <<= 1) mx = fmaxf(mx, __shfl_xor(mx, off));
    float sacc = __expf(aself - mx);
    float oacc = sacc * xl[(size_t)n * 64 + lane];
    int i = 0;
    for (; i + 2 <= m; i += 2) {                 // 2-way unroll: deeper load pipeline
        int s0 = src_idx[el[i]], s1 = src_idx[el[i + 1]];
        float a0 = asrc[s0 * 4 + h] + ad;
        float a1 = asrc[s1 * 4 + h] + ad;
        a0 = a0 > 0.f ? a0 : 0.2f * a0;
        a1 = a1 > 0.f ? a1 : 0.2f * a1;
        float e0 = __expf(a0 - mx), e1 = __expf(a1 - mx);
        sacc += e0 + e1;
        oacc += e0 * xl[(size_t)s0 * 64 + lane] + e1 * xl[(size_t)s1 * 64 + lane];
    }
    if (i < m) {
        int s = src_idx[el[i]];
        float a = asrc[s * 4 + h] + ad;
        a = a > 0.f ? a : 0.2f * a;
        float ea = __expf(a - mx);
        sacc += ea;
        oacc += ea * xl[(size_t)s * 64 + lane];
    }
    float r = oacc / sacc;
    r += __shfl_xor(r, 16);
    r += __shfl_xor(r, 32);
    if (lane < 16) out[(size_t)n * 16 + lane] = 0.25f * r + bias[lane];
}

extern "C" void kernel_launch(void* const* d_in, const int* in_sizes, int n_in,
                              void* d_out, int out_size, void* d_ws, size_t ws_size,
                              hipStream_t stream)
{
    const float* x     = (const float*)d_in[0];
    const int*   ei    = (const int*)  d_in[1];
    const float* eattr = (const float*)d_in[2];
    const float* hn_h  = (const float*)d_in[3];
    const float* hn_c  = (const float*)d_in[4];
    const float* he_h  = (const float*)d_in[5];
    const float* he_c  = (const float*)d_in[6];
    const float* Wih_n = (const float*)d_in[7];
    const float* Whh_n = (const float*)d_in[8];
    const float* bih_n = (const float*)d_in[9];
    const float* bhh_n = (const float*)d_in[10];
    const float* Wih_e = (const float*)d_in[11];
    const float* Whh_e = (const float*)d_in[12];
    const float* bih_e = (const float*)d_in[13];
    const float* bhh_e = (const float*)d_in[14];
    const float* W_gat = (const float*)d_in[15];
    const float* attS  = (const float*)d_in[16];
    const float* attD  = (const float*)d_in[17];
    const float* biasG = (const float*)d_in[18];

    const int N = in_sizes[0] / 5;
    const int E = in_sizes[2] / 2;

    float* out = (float*)d_out;
    float* hn  = out + (size_t)N * 16;
    float* cn  = hn  + (size_t)N * 128;
    float* he  = cn  + (size_t)N * 128;
    float* ce  = he  + (size_t)E * 32;

    char* p = (char*)d_ws;
    size_t off = 0;
    auto take = [&](size_t bytes) -> void* {
        void* r = p + off;
        off = (off + bytes + 255) & ~(size_t)255;
        return r;
    };
    int*   cnt  = (int*)  take((size_t)N * 4);
    int*   eid  = (int*)  take((size_t)N * CAP * 4);
    float* enc  = (float*)take((size_t)N * 32 * 4);
    float* xl   = (float*)take((size_t)N * 64 * 4);
    float* asrc = (float*)take((size_t)N * 4 * 4);
    float* adst = (float*)take((size_t)N * 4 * 4);
    unsigned short* Wn  = (unsigned short*)take(512 * 160 * 2);
    unsigned short* We  = (unsigned short*)take(128 * 64 * 2);
    unsigned short* Wgt = (unsigned short*)take(64 * 160 * 2);
    float* bsn = (float*)take(512 * 4);
    float* bse = (float*)take(128 * 4);

    hipMemsetAsync(cnt, 0, (size_t)N * 4, stream);
    convert_kernel<<<(512 * 160 + 255) / 256, 256, 0, stream>>>(
        Whh_n, Wih_n, bih_n, bhh_n, Whh_e, Wih_e, bih_e, bhh_e, W_gat,
        Wn, We, Wgt, bsn, bse);
    csr_fill_kernel<<<(E + 255) / 256, 256, 0, stream>>>(ei + E, cnt, eid, E);
    edge_lstm_mfma<<<(E + 255) / 256, 256, 0, stream>>>(
        eattr, he_h, he_c, We, bse, he, ce, E);
    node_lstm_mfma<<<(N + 63) / 64, 256, 0, stream>>>(
        x, hn_h, hn_c, Wn, bsn, hn, cn, N);
    edge_enc_kernel<<<(N + 3) / 4, 256, 0, stream>>>(cnt, eid, he, enc, N);
    gat_xl_mfma<<<(N + 63) / 64, 256, 0, stream>>>(
        hn, enc, Wgt, attS, attD, xl, asrc, adst, N);
    gat_node_kernel<<<(N + 3) / 4, 256, 0, stream>>>(
        cnt, eid, ei, asrc, adst, xl, biasG, out, N);
}

// Round 4
// 388.318 us; speedup vs baseline: 2.6311x; 1.2998x over previous
//
#include <hip/hip_runtime.h>

#define CAP 128  // max in-degree slots per node

typedef __attribute__((ext_vector_type(8))) short bf16x8;
typedef __attribute__((ext_vector_type(4))) float f32x4;

__device__ __forceinline__ float sigf(float x) {
    return __builtin_amdgcn_rcpf(1.0f + __expf(-x));
}
__device__ __forceinline__ float tanhfast(float x) {
    return 2.0f * __builtin_amdgcn_rcpf(1.0f + __expf(-2.0f * x)) - 1.0f;
}
__device__ __forceinline__ short bfr(float f) {          // fp32 -> bf16 RNE
    unsigned u = __float_as_uint(f);
    unsigned r = (u + 0x7FFFu + ((u >> 16) & 1u)) >> 16;
    return (short)r;
}
__device__ __forceinline__ bf16x8 cvt8(const float* p) { // 8 contiguous fp32 -> bf16x8
    const float4* q = (const float4*)p;
    float4 u = q[0], v = q[1];
    bf16x8 r;
    r[0]=bfr(u.x); r[1]=bfr(u.y); r[2]=bfr(u.z); r[3]=bfr(u.w);
    r[4]=bfr(v.x); r[5]=bfr(v.y); r[6]=bfr(v.z); r[7]=bfr(v.w);
    return r;
}

// ---------------- weight conversion: PER-LANE FRAGMENT ORDER ----------------
// layout: unit u = (t*K4 + k4)*64 + lane; element j in 0..7
// maps to  row = t*16 + (lane&15),  k = k4*32 + (lane>>4)*8 + j
// -> every wave fragment load is a contiguous 1KB burst.
__global__ void convert_kernel(
    const float* __restrict__ Whh_n, const float* __restrict__ Wih_n,
    const float* __restrict__ bih_n, const float* __restrict__ bhh_n,
    const float* __restrict__ Whh_e, const float* __restrict__ Wih_e,
    const float* __restrict__ bih_e, const float* __restrict__ bhh_e,
    const float* __restrict__ Wgat,
    unsigned short* __restrict__ WnF, unsigned short* __restrict__ WeF,
    unsigned short* __restrict__ WgF, float* __restrict__ bsn, float* __restrict__ bse)
{
    int i = blockIdx.x * 256 + threadIdx.x;
    if (i < 512 * 160) {                         // node: t 0..31, k4 0..4 (K=160)
        int j = i & 7, unit = i >> 3;
        int lane = unit & 63, tk = unit >> 6;
        int t = tk / 5, k4 = tk - t * 5;
        int r = t * 16 + (lane & 15);
        int k = k4 * 32 + (lane >> 4) * 8 + j;
        float v = (k < 128) ? Whh_n[r * 128 + k] : (k < 133 ? Wih_n[r * 5 + (k - 128)] : 0.f);
        WnF[i] = (unsigned short)bfr(v);
    }
    if (i < 128 * 64) {                          // edge: t 0..7, s 0..1 (K=64)
        int j = i & 7, unit = i >> 3;
        int lane = unit & 63, ts = unit >> 6;
        int t = ts >> 1, s = ts & 1;
        int r = t * 16 + (lane & 15);
        int k = s * 32 + (lane >> 4) * 8 + j;
        float v = (k < 32) ? Whh_e[r * 32 + k] : (k < 34 ? Wih_e[r * 2 + (k - 32)] : 0.f);
        WeF[i] = (unsigned short)bfr(v);
    }
    if (i < 64 * 160) {                          // gat (W^T): t 0..3, k4 0..4
        int j = i & 7, unit = i >> 3;
        int lane = unit & 63, tk = unit >> 6;
        int t = tk / 5, k4 = tk - t * 5;
        int r = t * 16 + (lane & 15);
        int k = k4 * 32 + (lane >> 4) * 8 + j;
        WgF[i] = (unsigned short)bfr(Wgat[k * 64 + r]);
    }
    if (i < 512) bsn[i] = bih_n[i] + bhh_n[i];
    if (i < 128) bse[i] = bih_e[i] + bhh_e[i];
}

// ---------------- capped per-dst edge list build ----------------
__global__ void csr_fill_kernel(const int* __restrict__ dst, int* __restrict__ cnt,
                                int* __restrict__ eid, int E)
{
    int e = blockIdx.x * blockDim.x + threadIdx.x;
    if (e >= E) return;
    int d = dst[e];
    int k = atomicAdd(cnt + d, 1);
    if (k < CAP) eid[(size_t)d * CAP + k] = e;
}

// ---------------- edge LSTM via MFMA (swapped: D[gate][edge]) ----------------
__global__ __launch_bounds__(256) void edge_lstm_mfma(
    const float* __restrict__ eattr, const float* __restrict__ h_in, const float* __restrict__ c_in,
    const unsigned short* __restrict__ WeF, const float* __restrict__ bse,
    float* __restrict__ he_out, float* __restrict__ ce_out, int E)
{
    const int lane = threadIdx.x & 63, wave = threadIdx.x >> 6;
    const int lr = lane & 15, lg = lane >> 4;
    const bf16x8* Wv = (const bf16x8*)WeF;
    bf16x8 wa0[8], wa1[8];
    #pragma unroll
    for (int t = 0; t < 8; ++t) {                // coalesced 1KB fragment bursts
        wa0[t] = Wv[(t * 2 + 0) * 64 + lane];
        wa1[t] = Wv[(t * 2 + 1) * 64 + lane];
    }
    const int jb0 = lg * 4, jb1 = 16 + lg * 4;
    const f32x4 bi0 = *(const f32x4*)(bse + jb0),       bi1 = *(const f32x4*)(bse + jb1);
    const f32x4 bf0 = *(const f32x4*)(bse + 32 + jb0),  bf1 = *(const f32x4*)(bse + 32 + jb1);
    const f32x4 bg0 = *(const f32x4*)(bse + 64 + jb0),  bg1 = *(const f32x4*)(bse + 64 + jb1);
    const f32x4 bo0 = *(const f32x4*)(bse + 96 + jb0),  bo1 = *(const f32x4*)(bse + 96 + jb1);
    const int base = blockIdx.x * 256 + wave * 64;
    #pragma unroll
    for (int tile = 0; tile < 4; ++tile) {
        const int e0 = base + tile * 16;
        if (e0 >= E) break;
        const int edge = e0 + lr;
        bf16x8 b0 = cvt8(h_in + (size_t)edge * 32 + lg * 8);
        bf16x8 b1 = {0,0,0,0,0,0,0,0};
        if (lg == 0) {
            b1[0] = bfr(eattr[(size_t)edge * 2]);
            b1[1] = bfr(eattr[(size_t)edge * 2 + 1]);
        }
        f32x4 acc[8];
        #pragma unroll
        for (int t = 0; t < 8; ++t) {
            f32x4 v = {0, 0, 0, 0};
            v = __builtin_amdgcn_mfma_f32_16x16x32_bf16(wa0[t], b0, v, 0, 0, 0);
            v = __builtin_amdgcn_mfma_f32_16x16x32_bf16(wa1[t], b1, v, 0, 0, 0);
            acc[t] = v;
        }
        #pragma unroll
        for (int u = 0; u < 2; ++u) {
            const int jb = u * 16 + lg * 4;
            const f32x4 bi = u ? bi1 : bi0, bf_ = u ? bf1 : bf0;
            const f32x4 bg_ = u ? bg1 : bg0, bo_ = u ? bo1 : bo0;
            f32x4 cold = *(const f32x4*)(c_in + (size_t)edge * 32 + jb);
            f32x4 cres, hres;
            #pragma unroll
            for (int q = 0; q < 4; ++q) {
                float gi = acc[u][q] + bi[q],      gf = acc[u + 2][q] + bf_[q];
                float gg = acc[u + 4][q] + bg_[q], go = acc[u + 6][q] + bo_[q];
                float c2 = sigf(gf) * cold[q] + sigf(gi) * tanhfast(gg);
                cres[q] = c2;
                hres[q] = sigf(go) * tanhfast(c2);
            }
            __builtin_nontemporal_store(cres, (f32x4*)(ce_out + (size_t)edge * 32 + jb));
            *(f32x4*)(he_out + (size_t)edge * 32 + jb) = hres;   // he re-read by edge_enc
        }
    }
}

// ---------------- node LSTM via MFMA (swapped): wave = 16 nodes, K=160 ----------------
__global__ __launch_bounds__(256) void node_lstm_mfma(
    const float* __restrict__ x, const float* __restrict__ h_in, const float* __restrict__ c_in,
    const unsigned short* __restrict__ WnF, const float* __restrict__ bsn,
    float* __restrict__ hn_out, float* __restrict__ cn_out, int N)
{
    const int lane = threadIdx.x & 63, wave = threadIdx.x >> 6;
    const int n0 = blockIdx.x * 64 + wave * 16;
    if (n0 >= N) return;                         // N % 16 == 0
    const int lr = lane & 15, lg = lane >> 4;
    const int node = n0 + lr;
    bf16x8 b[5];
    const float* hp = h_in + (size_t)node * 128 + lg * 8;
    b[0] = cvt8(hp); b[1] = cvt8(hp + 32); b[2] = cvt8(hp + 64); b[3] = cvt8(hp + 96);
    bf16x8 bx = {0,0,0,0,0,0,0,0};
    if (lg == 0) {
        const float* xp = x + (size_t)node * 5;
        bx[0]=bfr(xp[0]); bx[1]=bfr(xp[1]); bx[2]=bfr(xp[2]); bx[3]=bfr(xp[3]); bx[4]=bfr(xp[4]);
    }
    b[4] = bx;
    const bf16x8* Wv = (const bf16x8*)WnF;
    f32x4 acc[32];
    #pragma unroll
    for (int t = 0; t < 32; ++t) {
        const bf16x8* ap = Wv + t * 320 + lane;  // coalesced 1KB bursts
        f32x4 v = {0, 0, 0, 0};
        #pragma unroll
        for (int k4 = 0; k4 < 5; ++k4)
            v = __builtin_amdgcn_mfma_f32_16x16x32_bf16(ap[k4 * 64], b[k4], v, 0, 0, 0);
        acc[t] = v;
    }
    #pragma unroll
    for (int u = 0; u < 8; ++u) {
        const int jb = u * 16 + lg * 4;
        f32x4 bi  = *(const f32x4*)(bsn + jb);
        f32x4 bf_ = *(const f32x4*)(bsn + 128 + jb);
        f32x4 bg_ = *(const f32x4*)(bsn + 256 + jb);
        f32x4 bo_ = *(const f32x4*)(bsn + 384 + jb);
        f32x4 cold = *(const f32x4*)(c_in + (size_t)node * 128 + jb);
        f32x4 cres, hres;
        #pragma unroll
        for (int q = 0; q < 4; ++q) {
            float gi = acc[u][q] + bi[q],       gf = acc[u + 8][q] + bf_[q];
            float gg = acc[u + 16][q] + bg_[q], go = acc[u + 24][q] + bo_[q];
            float c2 = sigf(gf) * cold[q] + sigf(gi) * tanhfast(gg);
            cres[q] = c2;
            hres[q] = sigf(go) * tanhfast(c2);
        }
        __builtin_nontemporal_store(cres, (f32x4*)(cn_out + (size_t)node * 128 + jb));
        *(f32x4*)(hn_out + (size_t)node * 128 + jb) = hres;      // hn re-read by gat_xl
    }
}

// ---------------- scatter-mean: one wave per node, 8 rows in flight, float4 ----------------
__global__ __launch_bounds__(256) void edge_enc_kernel(
    const int* __restrict__ cnt, const int* __restrict__ eid,
    const float* __restrict__ he, float* __restrict__ enc, int N)
{
    const int wid = (blockIdx.x * blockDim.x + threadIdx.x) >> 6;
    const int lane = threadIdx.x & 63;
    if (wid >= N) return;
    const int c = cnt[wid];
    const int m = min(c, CAP);
    const int g = lane >> 3, l8 = lane & 7;      // 8 groups x 8 lanes x float4 = 128B row
    const int* el = eid + (size_t)wid * CAP;
    f32x4 acc = {0, 0, 0, 0};
    for (int i = g; i < m; i += 8)
        acc += *(const f32x4*)(he + (size_t)el[i] * 32 + l8 * 4);
    #pragma unroll
    for (int off = 8; off < 64; off <<= 1) {
        acc[0] += __shfl_xor(acc[0], off);
        acc[1] += __shfl_xor(acc[1], off);
        acc[2] += __shfl_xor(acc[2], off);
        acc[3] += __shfl_xor(acc[3], off);
    }
    if (g == 0) {
        float inv = 1.0f / fmaxf((float)c, 1.0f);
        f32x4 r; r[0]=acc[0]*inv; r[1]=acc[1]*inv; r[2]=acc[2]*inv; r[3]=acc[3]*inv;
        *(f32x4*)(enc + (size_t)wid * 32 + l8 * 4) = r;
    }
}

// ---------------- GAT linear via MFMA (swapped): wave = 16 nodes, K=160 ----------------
__global__ __launch_bounds__(256) void gat_xl_mfma(
    const float* __restrict__ hn, const float* __restrict__ enc,
    const unsigned short* __restrict__ WgF,
    const float* __restrict__ attS, const float* __restrict__ attD,
    float* __restrict__ xl, float* __restrict__ asrc, float* __restrict__ adst, int N)
{
    const int lane = threadIdx.x & 63, wave = threadIdx.x >> 6;
    const int n0 = blockIdx.x * 64 + wave * 16;
    if (n0 >= N) return;
    const int lr = lane & 15, lg = lane >> 4;
    const int node = n0 + lr;
    bf16x8 b[5];
    const float* hp = hn + (size_t)node * 128 + lg * 8;
    b[0] = cvt8(hp); b[1] = cvt8(hp + 32); b[2] = cvt8(hp + 64); b[3] = cvt8(hp + 96);
    b[4] = cvt8(enc + (size_t)node * 32 + lg * 8);
    const bf16x8* Wv = (const bf16x8*)WgF;
    #pragma unroll
    for (int t = 0; t < 4; ++t) {                // t = head
        const bf16x8* ap = Wv + t * 320 + lane;
        f32x4 v = {0, 0, 0, 0};
        #pragma unroll
        for (int k4 = 0; k4 < 5; ++k4)
            v = __builtin_amdgcn_mfma_f32_16x16x32_bf16(ap[k4 * 64], b[k4], v, 0, 0, 0);
        *(f32x4*)(xl + (size_t)node * 64 + t * 16 + lg * 4) = v;
        const f32x4 ws = *(const f32x4*)(attS + t * 16 + lg * 4);
        const f32x4 wd = *(const f32x4*)(attD + t * 16 + lg * 4);
        float p1 = v[0]*ws[0] + v[1]*ws[1] + v[2]*ws[2] + v[3]*ws[3];
        float p2 = v[0]*wd[0] + v[1]*wd[1] + v[2]*wd[2] + v[3]*wd[3];
        p1 += __shfl_xor(p1, 16); p2 += __shfl_xor(p2, 16);
        p1 += __shfl_xor(p1, 32); p2 += __shfl_xor(p2, 32);
        if (lg == 0) {
            asrc[(size_t)node * 4 + t] = p1;
            adst[(size_t)node * 4 + t] = p2;
        }
    }
}

// ---------------- fused GAT softmax + aggregation: one wave per node ----------------
// phase 1: slot-register (src, alpha); max-reduce; exp once. phase 2: shfl-broadcast + gather.
__global__ __launch_bounds__(256) void gat_node_kernel(
    const int* __restrict__ cnt, const int* __restrict__ eid,
    const int* __restrict__ src_idx,
    const float* __restrict__ asrc, const float* __restrict__ adst,
    const float* __restrict__ xl, const float* __restrict__ bias,
    float* __restrict__ out, int N)
{
    const int wid = (blockIdx.x * blockDim.x + threadIdx.x) >> 6;
    const int lane = threadIdx.x & 63;
    if (wid >= N) return;
    const int n = wid;
    const int m = min(cnt[n], CAP);
    const int h = lane >> 4, c16 = lane & 15;
    const int nslot = (m + 15) >> 4;             // <= 8
    const float ad = adst[n * 4 + h];
    float aself = asrc[n * 4 + h] + ad;
    aself = aself > 0.f ? aself : 0.2f * aself;
    const int* el = eid + (size_t)n * CAP;
    int   ss[8];
    float aa[8];
    float mx = aself;
    #pragma unroll
    for (int k = 0; k < 8; ++k) {
        if (k >= nslot) break;
        int i = k * 16 + c16;
        if (i < m) {
            int s = src_idx[el[i]];
            float a = asrc[s * 4 + h] + ad;
            a = a > 0.f ? a : 0.2f * a;
            ss[k] = s; aa[k] = a;
            mx = fmaxf(mx, a);
        } else { ss[k] = 0; aa[k] = -1e30f; }
    }
    #pragma unroll
    for (int off = 1; off < 16; off <<= 1) mx = fmaxf(mx, __shfl_xor(mx, off));
    float ea[8];
    float p = 0.f;
    #pragma unroll
    for (int k = 0; k < 8; ++k) {
        if (k >= nslot) break;
        ea[k] = __expf(aa[k] - mx);              // invalid slots -> exp(-huge) = 0
        p += ea[k];
    }
    #pragma unroll
    for (int off = 1; off < 16; off <<= 1) p += __shfl_xor(p, off);
    float eself = __expf(aself - mx);
    float sacc = eself + p;
    float oacc = eself * xl[(size_t)n * 64 + lane];
    const int grp = lane & 48;
    #pragma unroll
    for (int k = 0; k < 8; ++k) {
        if (k >= nslot) break;
        const int lim = min(16, m - k * 16);
        #pragma unroll 4
        for (int cc = 0; cc < lim; ++cc) {       // shfl-broadcast w,s within 16-lane group
            int srcl = grp | cc;
            float w = __shfl(ea[k], srcl);
            int   s = __shfl(ss[k], srcl);
            oacc += w * xl[(size_t)s * 64 + lane];
        }
    }
    float r = oacc / sacc;
    r += __shfl_xor(r, 16);                      // head mean
    r += __shfl_xor(r, 32);
    if (lane < 16) out[(size_t)n * 16 + lane] = 0.25f * r + bias[lane];
}

extern "C" void kernel_launch(void* const* d_in, const int* in_sizes, int n_in,
                              void* d_out, int out_size, void* d_ws, size_t ws_size,
                              hipStream_t stream)
{
    const float* x     = (const float*)d_in[0];
    const int*   ei    = (const int*)  d_in[1];
    const float* eattr = (const float*)d_in[2];
    const float* hn_h  = (const float*)d_in[3];
    const float* hn_c  = (const float*)d_in[4];
    const float* he_h  = (const float*)d_in[5];
    const float* he_c  = (const float*)d_in[6];
    const float* Wih_n = (const float*)d_in[7];
    const float* Whh_n = (const float*)d_in[8];
    const float* bih_n = (const float*)d_in[9];
    const float* bhh_n = (const float*)d_in[10];
    const float* Wih_e = (const float*)d_in[11];
    const float* Whh_e = (const float*)d_in[12];
    const float* bih_e = (const float*)d_in[13];
    const float* bhh_e = (const float*)d_in[14];
    const float* W_gat = (const float*)d_in[15];
    const float* attS  = (const float*)d_in[16];
    const float* attD  = (const float*)d_in[17];
    const float* biasG = (const float*)d_in[18];

    const int N = in_sizes[0] / 5;
    const int E = in_sizes[2] / 2;

    float* out = (float*)d_out;
    float* hn  = out + (size_t)N * 16;
    float* cn  = hn  + (size_t)N * 128;
    float* he  = cn  + (size_t)N * 128;
    float* ce  = he  + (size_t)E * 32;

    char* p = (char*)d_ws;
    size_t off = 0;
    auto take = [&](size_t bytes) -> void* {
        void* r = p + off;
        off = (off + bytes + 255) & ~(size_t)255;
        return r;
    };
    int*   cnt  = (int*)  take((size_t)N * 4);
    int*   eid  = (int*)  take((size_t)N * CAP * 4);
    float* enc  = (float*)take((size_t)N * 32 * 4);
    float* xl   = (float*)take((size_t)N * 64 * 4);
    float* asrc = (float*)take((size_t)N * 4 * 4);
    float* adst = (float*)take((size_t)N * 4 * 4);
    unsigned short* WnF = (unsigned short*)take(512 * 160 * 2);
    unsigned short* WeF = (unsigned short*)take(128 * 64 * 2);
    unsigned short* WgF = (unsigned short*)take(64 * 160 * 2);
    float* bsn = (float*)take(512 * 4);
    float* bse = (float*)take(128 * 4);

    hipMemsetAsync(cnt, 0, (size_t)N * 4, stream);
    convert_kernel<<<(512 * 160 + 255) / 256, 256, 0, stream>>>(
        Whh_n, Wih_n, bih_n, bhh_n, Whh_e, Wih_e, bih_e, bhh_e, W_gat,
        WnF, WeF, WgF, bsn, bse);
    csr_fill_kernel<<<(E + 255) / 256, 256, 0, stream>>>(ei + E, cnt, eid, E);
    edge_lstm_mfma<<<(E + 255) / 256, 256, 0, stream>>>(
        eattr, he_h, he_c, WeF, bse, he, ce, E);
    node_lstm_mfma<<<(N + 63) / 64, 256, 0, stream>>>(
        x, hn_h, hn_c, WnF, bsn, hn, cn, N);
    edge_enc_kernel<<<(N + 3) / 4, 256, 0, stream>>>(cnt, eid, he, enc, N);
    gat_xl_mfma<<<(N + 63) / 64, 256, 0, stream>>>(
        hn, enc, WgF, attS, attD, xl, asrc, adst, N);
    gat_node_kernel<<<(N + 3) / 4, 256, 0, stream>>>(
        cnt, eid, ei, asrc, adst, xl, biasG, out, N);
}

// Round 5
// 370.143 us; speedup vs baseline: 2.7603x; 1.0491x over previous
//
#include <hip/hip_runtime.h>

#define CAP 128  // max in-degree slots per node

typedef __attribute__((ext_vector_type(8))) short bf16x8;
typedef __attribute__((ext_vector_type(4))) float f32x4;

__device__ __forceinline__ float sigf(float x) {
    return __builtin_amdgcn_rcpf(1.0f + __expf(-x));
}
__device__ __forceinline__ float tanhfast(float x) {
    return 2.0f * __builtin_amdgcn_rcpf(1.0f + __expf(-2.0f * x)) - 1.0f;
}
__device__ __forceinline__ short bfr(float f) {          // fp32 -> bf16 RNE
    unsigned u = __float_as_uint(f);
    unsigned r = (u + 0x7FFFu + ((u >> 16) & 1u)) >> 16;
    return (short)r;
}
__device__ __forceinline__ float bf2f(unsigned short u) {
    return __uint_as_float(((unsigned)u) << 16);
}
__device__ __forceinline__ bf16x8 cvt8(const float* p) { // 8 contiguous fp32 -> bf16x8
    const float4* q = (const float4*)p;
    float4 u = q[0], v = q[1];
    bf16x8 r;
    r[0]=bfr(u.x); r[1]=bfr(u.y); r[2]=bfr(u.z); r[3]=bfr(u.w);
    r[4]=bfr(v.x); r[5]=bfr(v.y); r[6]=bfr(v.z); r[7]=bfr(v.w);
    return r;
}

// ---------------- weight conversion (fragment order) + cnt zeroing ----------------
__global__ void convert_kernel(
    const float* __restrict__ Whh_n, const float* __restrict__ Wih_n,
    const float* __restrict__ bih_n, const float* __restrict__ bhh_n,
    const float* __restrict__ Whh_e, const float* __restrict__ Wih_e,
    const float* __restrict__ bih_e, const float* __restrict__ bhh_e,
    const float* __restrict__ Wgat,
    unsigned short* __restrict__ WnF, unsigned short* __restrict__ WeF,
    unsigned short* __restrict__ WgF, float* __restrict__ bsn, float* __restrict__ bse,
    int* __restrict__ cnt, int N)
{
    int i = blockIdx.x * 256 + threadIdx.x;
    if (i < N) cnt[i] = 0;                       // replaces hipMemsetAsync
    if (i < 512 * 160) {                         // node: t 0..31, k4 0..4 (K=160)
        int j = i & 7, unit = i >> 3;
        int lane = unit & 63, tk = unit >> 6;
        int t = tk / 5, k4 = tk - t * 5;
        int r = t * 16 + (lane & 15);
        int k = k4 * 32 + (lane >> 4) * 8 + j;
        float v = (k < 128) ? Whh_n[r * 128 + k] : (k < 133 ? Wih_n[r * 5 + (k - 128)] : 0.f);
        WnF[i] = (unsigned short)bfr(v);
    }
    if (i < 128 * 64) {                          // edge: t 0..7, s 0..1 (K=64)
        int j = i & 7, unit = i >> 3;
        int lane = unit & 63, ts = unit >> 6;
        int t = ts >> 1, s = ts & 1;
        int r = t * 16 + (lane & 15);
        int k = s * 32 + (lane >> 4) * 8 + j;
        float v = (k < 32) ? Whh_e[r * 32 + k] : (k < 34 ? Wih_e[r * 2 + (k - 32)] : 0.f);
        WeF[i] = (unsigned short)bfr(v);
    }
    if (i < 64 * 160) {                          // gat (W^T): t 0..3, k4 0..4
        int j = i & 7, unit = i >> 3;
        int lane = unit & 63, tk = unit >> 6;
        int t = tk / 5, k4 = tk - t * 5;
        int r = t * 16 + (lane & 15);
        int k = k4 * 32 + (lane >> 4) * 8 + j;
        WgF[i] = (unsigned short)bfr(Wgat[k * 64 + r]);
    }
    if (i < 512) bsn[i] = bih_n[i] + bhh_n[i];
    if (i < 128) bse[i] = bih_e[i] + bhh_e[i];
}

// ---------------- edge LSTM via MFMA + fused csr build ----------------
__global__ __launch_bounds__(256) void edge_lstm_mfma(
    const float* __restrict__ eattr, const float* __restrict__ h_in, const float* __restrict__ c_in,
    const unsigned short* __restrict__ WeF, const float* __restrict__ bse,
    const int* __restrict__ dst, int* __restrict__ cnt, int* __restrict__ eid,
    float* __restrict__ he_out, float* __restrict__ ce_out, int E)
{
    const int lane = threadIdx.x & 63, wave = threadIdx.x >> 6;
    const int base = blockIdx.x * 256 + wave * 64;
    // fused csr: one coalesced dst read per wave; atomics fire-and-forget
    {
        const int edge = base + lane;
        if (edge < E) {
            int d = dst[edge];
            int k = atomicAdd(cnt + d, 1);
            if (k < CAP) eid[(size_t)d * CAP + k] = edge;
        }
    }
    const int lr = lane & 15, lg = lane >> 4;
    const bf16x8* Wv = (const bf16x8*)WeF;
    bf16x8 wa0[8], wa1[8];
    #pragma unroll
    for (int t = 0; t < 8; ++t) {                // coalesced 1KB fragment bursts
        wa0[t] = Wv[(t * 2 + 0) * 64 + lane];
        wa1[t] = Wv[(t * 2 + 1) * 64 + lane];
    }
    const int jb0 = lg * 4, jb1 = 16 + lg * 4;
    const f32x4 bi0 = *(const f32x4*)(bse + jb0),       bi1 = *(const f32x4*)(bse + jb1);
    const f32x4 bf0 = *(const f32x4*)(bse + 32 + jb0),  bf1 = *(const f32x4*)(bse + 32 + jb1);
    const f32x4 bg0 = *(const f32x4*)(bse + 64 + jb0),  bg1 = *(const f32x4*)(bse + 64 + jb1);
    const f32x4 bo0 = *(const f32x4*)(bse + 96 + jb0),  bo1 = *(const f32x4*)(bse + 96 + jb1);
    #pragma unroll
    for (int tile = 0; tile < 4; ++tile) {
        const int e0 = base + tile * 16;
        if (e0 >= E) break;                      // E % 16 == 0
        const int edge = e0 + lr;
        bf16x8 b0 = cvt8(h_in + (size_t)edge * 32 + lg * 8);
        bf16x8 b1 = {0,0,0,0,0,0,0,0};
        if (lg == 0) {
            b1[0] = bfr(eattr[(size_t)edge * 2]);
            b1[1] = bfr(eattr[(size_t)edge * 2 + 1]);
        }
        f32x4 acc[8];
        #pragma unroll
        for (int t = 0; t < 8; ++t) {
            f32x4 v = {0, 0, 0, 0};
            v = __builtin_amdgcn_mfma_f32_16x16x32_bf16(wa0[t], b0, v, 0, 0, 0);
            v = __builtin_amdgcn_mfma_f32_16x16x32_bf16(wa1[t], b1, v, 0, 0, 0);
            acc[t] = v;
        }
        #pragma unroll
        for (int u = 0; u < 2; ++u) {
            const int jb = u * 16 + lg * 4;
            const f32x4 bi = u ? bi1 : bi0, bf_ = u ? bf1 : bf0;
            const f32x4 bg_ = u ? bg1 : bg0, bo_ = u ? bo1 : bo0;
            f32x4 cold = *(const f32x4*)(c_in + (size_t)edge * 32 + jb);
            f32x4 cres, hres;
            #pragma unroll
            for (int q = 0; q < 4; ++q) {
                float gi = acc[u][q] + bi[q],      gf = acc[u + 2][q] + bf_[q];
                float gg = acc[u + 4][q] + bg_[q], go = acc[u + 6][q] + bo_[q];
                float c2 = sigf(gf) * cold[q] + sigf(gi) * tanhfast(gg);
                cres[q] = c2;
                hres[q] = sigf(go) * tanhfast(c2);
            }
            __builtin_nontemporal_store(cres, (f32x4*)(ce_out + (size_t)edge * 32 + jb));
            *(f32x4*)(he_out + (size_t)edge * 32 + jb) = hres;   // he re-read by enc gather
        }
    }
}

// ---------------- node LSTM via MFMA: wave = 16 nodes, K=160 ----------------
__global__ __launch_bounds__(256) void node_lstm_mfma(
    const float* __restrict__ x, const float* __restrict__ h_in, const float* __restrict__ c_in,
    const unsigned short* __restrict__ WnF, const float* __restrict__ bsn,
    float* __restrict__ hn_out, float* __restrict__ cn_out, int N)
{
    const int lane = threadIdx.x & 63, wave = threadIdx.x >> 6;
    const int n0 = blockIdx.x * 64 + wave * 16;
    if (n0 >= N) return;                         // N % 16 == 0
    const int lr = lane & 15, lg = lane >> 4;
    const int node = n0 + lr;
    bf16x8 b[5];
    const float* hp = h_in + (size_t)node * 128 + lg * 8;
    b[0] = cvt8(hp); b[1] = cvt8(hp + 32); b[2] = cvt8(hp + 64); b[3] = cvt8(hp + 96);
    bf16x8 bx = {0,0,0,0,0,0,0,0};
    if (lg == 0) {
        const float* xp = x + (size_t)node * 5;
        bx[0]=bfr(xp[0]); bx[1]=bfr(xp[1]); bx[2]=bfr(xp[2]); bx[3]=bfr(xp[3]); bx[4]=bfr(xp[4]);
    }
    b[4] = bx;
    const bf16x8* Wv = (const bf16x8*)WnF;
    f32x4 acc[32];
    #pragma unroll
    for (int t = 0; t < 32; ++t) {
        const bf16x8* ap = Wv + t * 320 + lane;  // coalesced 1KB bursts
        f32x4 v = {0, 0, 0, 0};
        #pragma unroll
        for (int k4 = 0; k4 < 5; ++k4)
            v = __builtin_amdgcn_mfma_f32_16x16x32_bf16(ap[k4 * 64], b[k4], v, 0, 0, 0);
        acc[t] = v;
    }
    #pragma unroll
    for (int u = 0; u < 8; ++u) {
        const int jb = u * 16 + lg * 4;
        f32x4 bi  = *(const f32x4*)(bsn + jb);
        f32x4 bf_ = *(const f32x4*)(bsn + 128 + jb);
        f32x4 bg_ = *(const f32x4*)(bsn + 256 + jb);
        f32x4 bo_ = *(const f32x4*)(bsn + 384 + jb);
        f32x4 cold = *(const f32x4*)(c_in + (size_t)node * 128 + jb);
        f32x4 cres, hres;
        #pragma unroll
        for (int q = 0; q < 4; ++q) {
            float gi = acc[u][q] + bi[q],       gf = acc[u + 8][q] + bf_[q];
            float gg = acc[u + 16][q] + bg_[q], go = acc[u + 24][q] + bo_[q];
            float c2 = sigf(gf) * cold[q] + sigf(gi) * tanhfast(gg);
            cres[q] = c2;
            hres[q] = sigf(go) * tanhfast(c2);
        }
        __builtin_nontemporal_store(cres, (f32x4*)(cn_out + (size_t)node * 128 + jb));
        *(f32x4*)(hn_out + (size_t)node * 128 + jb) = hres;      // hn re-read below
    }
}

// ---------------- fused edge_enc (LDS-only) + GAT linear: block = 64 nodes ----------------
// phase A: wave computes scatter-mean enc for its 16 nodes into LDS (wave-private, no barrier)
// phase B: MFMA [16 x 160] @ [160 x 64]; xl stored bf16; attention logits via butterfly
__global__ __launch_bounds__(256) void enc_gatxl_kernel(
    const int* __restrict__ cnt, const int* __restrict__ eid, const float* __restrict__ he,
    const float* __restrict__ hn, const unsigned short* __restrict__ WgF,
    const float* __restrict__ attS, const float* __restrict__ attD,
    unsigned short* __restrict__ xlb, float* __restrict__ asrc, float* __restrict__ adst, int N)
{
    __shared__ float encs[64 * 36];              // row stride 36: 2-way max bank alias
    const int lane = threadIdx.x & 63, wave = threadIdx.x >> 6;
    const int nbase = blockIdx.x * 64 + wave * 16;
    if (nbase >= N) return;                      // N % 16 == 0 -> wave-uniform
    // ---- phase A ----
    const int g = lane >> 3, l8 = lane & 7;      // 8 groups x 8 lanes x float4
    for (int t = 0; t < 16; ++t) {
        const int node = nbase + t;
        const int c = cnt[node];
        const int m = min(c, CAP);
        const int* el = eid + (size_t)node * CAP;
        f32x4 acc = {0, 0, 0, 0};
        for (int i = g; i < m; i += 8)
            acc += *(const f32x4*)(he + (size_t)el[i] * 32 + l8 * 4);
        #pragma unroll
        for (int off = 8; off < 64; off <<= 1) {
            acc[0] += __shfl_xor(acc[0], off);
            acc[1] += __shfl_xor(acc[1], off);
            acc[2] += __shfl_xor(acc[2], off);
            acc[3] += __shfl_xor(acc[3], off);
        }
        if (g == 0) {
            float inv = 1.0f / fmaxf((float)c, 1.0f);
            f32x4 r; r[0]=acc[0]*inv; r[1]=acc[1]*inv; r[2]=acc[2]*inv; r[3]=acc[3]*inv;
            *(f32x4*)(&encs[(wave * 16 + t) * 36 + l8 * 4]) = r;
        }
    }
    // ---- phase B (same wave consumes its own enc rows; no __syncthreads) ----
    const int lr = lane & 15, lg = lane >> 4;
    const int node = nbase + lr;
    bf16x8 b[5];
    const float* hp = hn + (size_t)node * 128 + lg * 8;
    b[0] = cvt8(hp); b[1] = cvt8(hp + 32); b[2] = cvt8(hp + 64); b[3] = cvt8(hp + 96);
    b[4] = cvt8(&encs[(wave * 16 + lr) * 36 + lg * 8]);
    const bf16x8* Wv = (const bf16x8*)WgF;
    #pragma unroll
    for (int t = 0; t < 4; ++t) {                // t = head
        const bf16x8* ap = Wv + t * 320 + lane;
        f32x4 v = {0, 0, 0, 0};
        #pragma unroll
        for (int k4 = 0; k4 < 5; ++k4)
            v = __builtin_amdgcn_mfma_f32_16x16x32_bf16(ap[k4 * 64], b[k4], v, 0, 0, 0);
        ushort4 pk;
        pk.x = (unsigned short)bfr(v[0]); pk.y = (unsigned short)bfr(v[1]);
        pk.z = (unsigned short)bfr(v[2]); pk.w = (unsigned short)bfr(v[3]);
        *(ushort4*)(xlb + (size_t)node * 64 + t * 16 + lg * 4) = pk;
        const f32x4 ws = *(const f32x4*)(attS + t * 16 + lg * 4);
        const f32x4 wd = *(const f32x4*)(attD + t * 16 + lg * 4);
        float p1 = v[0]*ws[0] + v[1]*ws[1] + v[2]*ws[2] + v[3]*ws[3];
        float p2 = v[0]*wd[0] + v[1]*wd[1] + v[2]*wd[2] + v[3]*wd[3];
        p1 += __shfl_xor(p1, 16); p2 += __shfl_xor(p2, 16);
        p1 += __shfl_xor(p1, 32); p2 += __shfl_xor(p2, 32);
        if (lg == 0) {
            asrc[(size_t)node * 4 + t] = p1;
            adst[(size_t)node * 4 + t] = p2;
        }
    }
}

// ---------------- fused GAT softmax + aggregation: one wave per node, bf16 xl ----------------
__global__ __launch_bounds__(256) void gat_node_kernel(
    const int* __restrict__ cnt, const int* __restrict__ eid,
    const int* __restrict__ src_idx,
    const float* __restrict__ asrc, const float* __restrict__ adst,
    const unsigned short* __restrict__ xlb, const float* __restrict__ bias,
    float* __restrict__ out, int N)
{
    const int wid = (blockIdx.x * blockDim.x + threadIdx.x) >> 6;
    const int lane = threadIdx.x & 63;
    if (wid >= N) return;
    const int n = wid;
    const int m = min(cnt[n], CAP);
    const int h = lane >> 4, c16 = lane & 15;
    const int nslot = (m + 15) >> 4;             // <= 8
    const float ad = adst[n * 4 + h];
    float aself = asrc[n * 4 + h] + ad;
    aself = aself > 0.f ? aself : 0.2f * aself;
    const int* el = eid + (size_t)n * CAP;
    int   ss[8];
    float aa[8];
    float mx = aself;
    #pragma unroll
    for (int k = 0; k < 8; ++k) {
        if (k >= nslot) break;
        int i = k * 16 + c16;
        if (i < m) {
            int s = src_idx[el[i]];
            float a = asrc[s * 4 + h] + ad;
            a = a > 0.f ? a : 0.2f * a;
            ss[k] = s; aa[k] = a;
            mx = fmaxf(mx, a);
        } else { ss[k] = 0; aa[k] = -1e30f; }
    }
    #pragma unroll
    for (int off = 1; off < 16; off <<= 1) mx = fmaxf(mx, __shfl_xor(mx, off));
    float ea[8];
    float p = 0.f;
    #pragma unroll
    for (int k = 0; k < 8; ++k) {
        if (k >= nslot) break;
        ea[k] = __expf(aa[k] - mx);
        p += ea[k];
    }
    #pragma unroll
    for (int off = 1; off < 16; off <<= 1) p += __shfl_xor(p, off);
    float eself = __expf(aself - mx);
    float sacc = eself + p;
    float oacc = eself * bf2f(xlb[(size_t)n * 64 + lane]);
    const int grp = lane & 48;
    #pragma unroll
    for (int k = 0; k < 8; ++k) {
        if (k >= nslot) break;
        const int lim = min(16, m - k * 16);
        #pragma unroll 4
        for (int cc = 0; cc < lim; ++cc) {
            int srcl = grp | cc;
            float w = __shfl(ea[k], srcl);
            int   s = __shfl(ss[k], srcl);
            oacc += w * bf2f(xlb[(size_t)s * 64 + lane]);
        }
    }
    float r = oacc / sacc;
    r += __shfl_xor(r, 16);                      // head mean
    r += __shfl_xor(r, 32);
    if (lane < 16) out[(size_t)n * 16 + lane] = 0.25f * r + bias[lane];
}

extern "C" void kernel_launch(void* const* d_in, const int* in_sizes, int n_in,
                              void* d_out, int out_size, void* d_ws, size_t ws_size,
                              hipStream_t stream)
{
    const float* x     = (const float*)d_in[0];
    const int*   ei    = (const int*)  d_in[1];
    const float* eattr = (const float*)d_in[2];
    const float* hn_h  = (const float*)d_in[3];
    const float* hn_c  = (const float*)d_in[4];
    const float* he_h  = (const float*)d_in[5];
    const float* he_c  = (const float*)d_in[6];
    const float* Wih_n = (const float*)d_in[7];
    const float* Whh_n = (const float*)d_in[8];
    const float* bih_n = (const float*)d_in[9];
    const float* bhh_n = (const float*)d_in[10];
    const float* Wih_e = (const float*)d_in[11];
    const float* Whh_e = (const float*)d_in[12];
    const float* bih_e = (const float*)d_in[13];
    const float* bhh_e = (const float*)d_in[14];
    const float* W_gat = (const float*)d_in[15];
    const float* attS  = (const float*)d_in[16];
    const float* attD  = (const float*)d_in[17];
    const float* biasG = (const float*)d_in[18];

    const int N = in_sizes[0] / 5;
    const int E = in_sizes[2] / 2;

    float* out = (float*)d_out;
    float* hn  = out + (size_t)N * 16;
    float* cn  = hn  + (size_t)N * 128;
    float* he  = cn  + (size_t)N * 128;
    float* ce  = he  + (size_t)E * 32;

    char* p = (char*)d_ws;
    size_t off = 0;
    auto take = [&](size_t bytes) -> void* {
        void* r = p + off;
        off = (off + bytes + 255) & ~(size_t)255;
        return r;
    };
    int*   cnt  = (int*)  take((size_t)N * 4);
    int*   eid  = (int*)  take((size_t)N * CAP * 4);
    unsigned short* xlb = (unsigned short*)take((size_t)N * 64 * 2);
    float* asrc = (float*)take((size_t)N * 4 * 4);
    float* adst = (float*)take((size_t)N * 4 * 4);
    unsigned short* WnF = (unsigned short*)take(512 * 160 * 2);
    unsigned short* WeF = (unsigned short*)take(128 * 64 * 2);
    unsigned short* WgF = (unsigned short*)take(64 * 160 * 2);
    float* bsn = (float*)take(512 * 4);
    float* bse = (float*)take(128 * 4);

    convert_kernel<<<(512 * 160 + 255) / 256, 256, 0, stream>>>(
        Whh_n, Wih_n, bih_n, bhh_n, Whh_e, Wih_e, bih_e, bhh_e, W_gat,
        WnF, WeF, WgF, bsn, bse, cnt, N);
    edge_lstm_mfma<<<(E + 255) / 256, 256, 0, stream>>>(
        eattr, he_h, he_c, WeF, bse, ei + E, cnt, eid, he, ce, E);
    node_lstm_mfma<<<(N + 63) / 64, 256, 0, stream>>>(
        x, hn_h, hn_c, WnF, bsn, hn, cn, N);
    enc_gatxl_kernel<<<(N + 63) / 64, 256, 0, stream>>>(
        cnt, eid, he, hn, WgF, attS, attD, xlb, asrc, adst, N);
    gat_node_kernel<<<(N + 3) / 4, 256, 0, stream>>>(
        cnt, eid, ei, asrc, adst, xlb, biasG, out, N);
}

// Round 6
// 361.712 us; speedup vs baseline: 2.8246x; 1.0233x over previous
//
#include <hip/hip_runtime.h>

#define CAP 128  // max in-degree slots per node

typedef __attribute__((ext_vector_type(8))) short bf16x8;
typedef __attribute__((ext_vector_type(4))) float f32x4;

__device__ __forceinline__ float sigf(float x) {
    return __builtin_amdgcn_rcpf(1.0f + __expf(-x));
}
__device__ __forceinline__ float tanhfast(float x) {
    return 2.0f * __builtin_amdgcn_rcpf(1.0f + __expf(-2.0f * x)) - 1.0f;
}
__device__ __forceinline__ short bfr(float f) {          // fp32 -> bf16 RNE
    unsigned u = __float_as_uint(f);
    unsigned r = (u + 0x7FFFu + ((u >> 16) & 1u)) >> 16;
    return (short)r;
}
__device__ __forceinline__ float bf2f(unsigned short u) {
    return __uint_as_float(((unsigned)u) << 16);
}
__device__ __forceinline__ bf16x8 cvt8(const float* p) { // 8 contiguous fp32 -> bf16x8
    const float4* q = (const float4*)p;
    float4 u = q[0], v = q[1];
    bf16x8 r;
    r[0]=bfr(u.x); r[1]=bfr(u.y); r[2]=bfr(u.z); r[3]=bfr(u.w);
    r[4]=bfr(v.x); r[5]=bfr(v.y); r[6]=bfr(v.z); r[7]=bfr(v.w);
    return r;
}

// ---------------- weight conversion (fragment order) + cnt zeroing ----------------
__global__ void convert_kernel(
    const float* __restrict__ Whh_n, const float* __restrict__ Wih_n,
    const float* __restrict__ bih_n, const float* __restrict__ bhh_n,
    const float* __restrict__ Whh_e, const float* __restrict__ Wih_e,
    const float* __restrict__ bih_e, const float* __restrict__ bhh_e,
    const float* __restrict__ Wgat,
    unsigned short* __restrict__ WnF, unsigned short* __restrict__ WeF,
    unsigned short* __restrict__ WgF, float* __restrict__ bsn, float* __restrict__ bse,
    int* __restrict__ cnt, int N)
{
    int i = blockIdx.x * 256 + threadIdx.x;
    if (i < N) cnt[i] = 0;                       // replaces hipMemsetAsync
    if (i < 512 * 160) {                         // node: t 0..31, k4 0..4 (K=160)
        int j = i & 7, unit = i >> 3;
        int lane = unit & 63, tk = unit >> 6;
        int t = tk / 5, k4 = tk - t * 5;
        int r = t * 16 + (lane & 15);
        int k = k4 * 32 + (lane >> 4) * 8 + j;
        float v = (k < 128) ? Whh_n[r * 128 + k] : (k < 133 ? Wih_n[r * 5 + (k - 128)] : 0.f);
        WnF[i] = (unsigned short)bfr(v);
    }
    if (i < 128 * 64) {                          // edge: t 0..7, s 0..1 (K=64)
        int j = i & 7, unit = i >> 3;
        int lane = unit & 63, ts = unit >> 6;
        int t = ts >> 1, s = ts & 1;
        int r = t * 16 + (lane & 15);
        int k = s * 32 + (lane >> 4) * 8 + j;
        float v = (k < 32) ? Whh_e[r * 32 + k] : (k < 34 ? Wih_e[r * 2 + (k - 32)] : 0.f);
        WeF[i] = (unsigned short)bfr(v);
    }
    if (i < 64 * 160) {                          // gat (W^T): t 0..3, k4 0..4
        int j = i & 7, unit = i >> 3;
        int lane = unit & 63, tk = unit >> 6;
        int t = tk / 5, k4 = tk - t * 5;
        int r = t * 16 + (lane & 15);
        int k = k4 * 32 + (lane >> 4) * 8 + j;
        WgF[i] = (unsigned short)bfr(Wgat[k * 64 + r]);
    }
    if (i < 512) bsn[i] = bih_n[i] + bhh_n[i];
    if (i < 128) bse[i] = bih_e[i] + bhh_e[i];
}

// ---------------- edge LSTM via MFMA; csr build at kernel END (vmcnt-FIFO safe) ----------------
__global__ __launch_bounds__(256) void edge_lstm_mfma(
    const float* __restrict__ eattr, const float* __restrict__ h_in, const float* __restrict__ c_in,
    const unsigned short* __restrict__ WeF, const float* __restrict__ bse,
    const int* __restrict__ dst, int* __restrict__ cnt, int* __restrict__ eid,
    float* __restrict__ he_out, float* __restrict__ ce_out, int E)
{
    const int lane = threadIdx.x & 63, wave = threadIdx.x >> 6;
    const int base = blockIdx.x * 256 + wave * 64;
    if (base >= E) return;
    const int lr = lane & 15, lg = lane >> 4;
    // prologue: issue csr dst load + ALL 4 tiles' b-fragment loads (max MLP)
    const int cedge = base + lane;
    const int d = (cedge < E) ? dst[cedge] : -1;
    bf16x8 b0[4], b1[4];
    #pragma unroll
    for (int t = 0; t < 4; ++t) {
        const int edge = base + t * 16 + lr;
        b0[t] = cvt8(h_in + (size_t)edge * 32 + lg * 8);
        bf16x8 bb = {0,0,0,0,0,0,0,0};
        if (lg == 0) {
            bb[0] = bfr(eattr[(size_t)edge * 2]);
            bb[1] = bfr(eattr[(size_t)edge * 2 + 1]);
        }
        b1[t] = bb;
    }
    // weights: coalesced 1KB fragment bursts (L2-hot after first blocks)
    const bf16x8* Wv = (const bf16x8*)WeF;
    bf16x8 wa0[8], wa1[8];
    #pragma unroll
    for (int t = 0; t < 8; ++t) {
        wa0[t] = Wv[(t * 2 + 0) * 64 + lane];
        wa1[t] = Wv[(t * 2 + 1) * 64 + lane];
    }
    const int jb0 = lg * 4, jb1 = 16 + lg * 4;
    const f32x4 bi0 = *(const f32x4*)(bse + jb0),       bi1 = *(const f32x4*)(bse + jb1);
    const f32x4 bf0 = *(const f32x4*)(bse + 32 + jb0),  bf1 = *(const f32x4*)(bse + 32 + jb1);
    const f32x4 bg0 = *(const f32x4*)(bse + 64 + jb0),  bg1 = *(const f32x4*)(bse + 64 + jb1);
    const f32x4 bo0 = *(const f32x4*)(bse + 96 + jb0),  bo1 = *(const f32x4*)(bse + 96 + jb1);
    #pragma unroll
    for (int tile = 0; tile < 4; ++tile) {
        const int edge = base + tile * 16 + lr;
        // c loads issue here; MFMA below runs from regs (no vmcnt wait in between)
        f32x4 cold0 = *(const f32x4*)(c_in + (size_t)edge * 32 + jb0);
        f32x4 cold1 = *(const f32x4*)(c_in + (size_t)edge * 32 + jb1);
        f32x4 acc[8];
        #pragma unroll
        for (int t = 0; t < 8; ++t) {
            f32x4 v = {0, 0, 0, 0};
            v = __builtin_amdgcn_mfma_f32_16x16x32_bf16(wa0[t], b0[tile], v, 0, 0, 0);
            v = __builtin_amdgcn_mfma_f32_16x16x32_bf16(wa1[t], b1[tile], v, 0, 0, 0);
            acc[t] = v;
        }
        #pragma unroll
        for (int u = 0; u < 2; ++u) {
            const int jb = u ? jb1 : jb0;
            const f32x4 bi = u ? bi1 : bi0, bf_ = u ? bf1 : bf0;
            const f32x4 bg_ = u ? bg1 : bg0, bo_ = u ? bo1 : bo0;
            const f32x4 cold = u ? cold1 : cold0;
            f32x4 cres, hres;
            #pragma unroll
            for (int q = 0; q < 4; ++q) {
                float gi = acc[u][q] + bi[q],      gf = acc[u + 2][q] + bf_[q];
                float gg = acc[u + 4][q] + bg_[q], go = acc[u + 6][q] + bo_[q];
                float c2 = sigf(gf) * cold[q] + sigf(gi) * tanhfast(gg);
                cres[q] = c2;
                hres[q] = sigf(go) * tanhfast(c2);
            }
            __builtin_nontemporal_store(cres, (f32x4*)(ce_out + (size_t)edge * 32 + jb));
            *(f32x4*)(he_out + (size_t)edge * 32 + jb) = hres;   // he re-read by enc gather
        }
    }
    // csr tail: atomic latency invisible — nothing downstream waits on it
    if (d >= 0) {
        int k = atomicAdd(cnt + d, 1);
        if (k < CAP) eid[(size_t)d * CAP + k] = cedge;
    }
}

// ---------------- node LSTM via MFMA: wave = 16 nodes, K=160 ----------------
__global__ __launch_bounds__(256) void node_lstm_mfma(
    const float* __restrict__ x, const float* __restrict__ h_in, const float* __restrict__ c_in,
    const unsigned short* __restrict__ WnF, const float* __restrict__ bsn,
    float* __restrict__ hn_out, float* __restrict__ cn_out, int N)
{
    const int lane = threadIdx.x & 63, wave = threadIdx.x >> 6;
    const int n0 = blockIdx.x * 64 + wave * 16;
    if (n0 >= N) return;                         // N % 16 == 0
    const int lr = lane & 15, lg = lane >> 4;
    const int node = n0 + lr;
    bf16x8 b[5];
    const float* hp = h_in + (size_t)node * 128 + lg * 8;
    b[0] = cvt8(hp); b[1] = cvt8(hp + 32); b[2] = cvt8(hp + 64); b[3] = cvt8(hp + 96);
    bf16x8 bx = {0,0,0,0,0,0,0,0};
    if (lg == 0) {
        const float* xp = x + (size_t)node * 5;
        bx[0]=bfr(xp[0]); bx[1]=bfr(xp[1]); bx[2]=bfr(xp[2]); bx[3]=bfr(xp[3]); bx[4]=bfr(xp[4]);
    }
    b[4] = bx;
    const bf16x8* Wv = (const bf16x8*)WnF;
    f32x4 acc[32];
    #pragma unroll
    for (int t = 0; t < 32; ++t) {
        const bf16x8* ap = Wv + t * 320 + lane;  // coalesced 1KB bursts
        f32x4 v = {0, 0, 0, 0};
        #pragma unroll
        for (int k4 = 0; k4 < 5; ++k4)
            v = __builtin_amdgcn_mfma_f32_16x16x32_bf16(ap[k4 * 64], b[k4], v, 0, 0, 0);
        acc[t] = v;
    }
    #pragma unroll
    for (int u = 0; u < 8; ++u) {
        const int jb = u * 16 + lg * 4;
        f32x4 bi  = *(const f32x4*)(bsn + jb);
        f32x4 bf_ = *(const f32x4*)(bsn + 128 + jb);
        f32x4 bg_ = *(const f32x4*)(bsn + 256 + jb);
        f32x4 bo_ = *(const f32x4*)(bsn + 384 + jb);
        f32x4 cold = *(const f32x4*)(c_in + (size_t)node * 128 + jb);
        f32x4 cres, hres;
        #pragma unroll
        for (int q = 0; q < 4; ++q) {
            float gi = acc[u][q] + bi[q],       gf = acc[u + 8][q] + bf_[q];
            float gg = acc[u + 16][q] + bg_[q], go = acc[u + 24][q] + bo_[q];
            float c2 = sigf(gf) * cold[q] + sigf(gi) * tanhfast(gg);
            cres[q] = c2;
            hres[q] = sigf(go) * tanhfast(c2);
        }
        __builtin_nontemporal_store(cres, (f32x4*)(cn_out + (size_t)node * 128 + jb));
        *(f32x4*)(hn_out + (size_t)node * 128 + jb) = hres;      // hn re-read below
    }
}

// ---------------- fused edge_enc (LDS-only) + GAT linear: block = 64 nodes ----------------
// phase A: 2 nodes per iteration (32 lanes each) -> halved serial chain
// phase B: MFMA [16 x 160] @ [160 x 64]; xl stored bf16; logits via butterfly
__global__ __launch_bounds__(256) void enc_gatxl_kernel(
    const int* __restrict__ cnt, const int* __restrict__ eid, const float* __restrict__ he,
    const float* __restrict__ hn, const unsigned short* __restrict__ WgF,
    const float* __restrict__ attS, const float* __restrict__ attD,
    unsigned short* __restrict__ xlb, float* __restrict__ asrc, float* __restrict__ adst, int N)
{
    __shared__ float encs[64 * 36];              // row stride 36: 2-way max bank alias
    const int lane = threadIdx.x & 63, wave = threadIdx.x >> 6;
    const int nbase = blockIdx.x * 64 + wave * 16;
    if (nbase >= N) return;                      // N % 16 == 0 -> wave-uniform
    // ---- phase A: lanes 0-31 -> node t, lanes 32-63 -> node t+1 ----
    const int half = lane >> 5, hl = lane & 31;
    const int g4 = hl >> 3, l8 = hl & 7;         // 4 groups x 8 lanes x float4
    for (int t = 0; t < 16; t += 2) {
        const int node = nbase + t + half;
        const int c = cnt[node];
        const int m = min(c, CAP);
        const int* el = eid + (size_t)node * CAP;
        f32x4 acc = {0, 0, 0, 0};
        for (int i = g4; i < m; i += 4)
            acc += *(const f32x4*)(he + (size_t)el[i] * 32 + l8 * 4);
        #pragma unroll
        for (int off = 8; off <= 16; off <<= 1) {    // reduce within 32-lane half
            acc[0] += __shfl_xor(acc[0], off);
            acc[1] += __shfl_xor(acc[1], off);
            acc[2] += __shfl_xor(acc[2], off);
            acc[3] += __shfl_xor(acc[3], off);
        }
        if (g4 == 0) {
            float inv = 1.0f / fmaxf((float)c, 1.0f);
            f32x4 r; r[0]=acc[0]*inv; r[1]=acc[1]*inv; r[2]=acc[2]*inv; r[3]=acc[3]*inv;
            *(f32x4*)(&encs[(wave * 16 + t + half) * 36 + l8 * 4]) = r;
        }
    }
    // ---- phase B (same wave consumes its own enc rows; no __syncthreads) ----
    const int lr = lane & 15, lg = lane >> 4;
    const int node = nbase + lr;
    bf16x8 b[5];
    const float* hp = hn + (size_t)node * 128 + lg * 8;
    b[0] = cvt8(hp); b[1] = cvt8(hp + 32); b[2] = cvt8(hp + 64); b[3] = cvt8(hp + 96);
    b[4] = cvt8(&encs[(wave * 16 + lr) * 36 + lg * 8]);
    const bf16x8* Wv = (const bf16x8*)WgF;
    #pragma unroll
    for (int t = 0; t < 4; ++t) {                // t = head
        const bf16x8* ap = Wv + t * 320 + lane;
        f32x4 v = {0, 0, 0, 0};
        #pragma unroll
        for (int k4 = 0; k4 < 5; ++k4)
            v = __builtin_amdgcn_mfma_f32_16x16x32_bf16(ap[k4 * 64], b[k4], v, 0, 0, 0);
        ushort4 pk;
        pk.x = (unsigned short)bfr(v[0]); pk.y = (unsigned short)bfr(v[1]);
        pk.z = (unsigned short)bfr(v[2]); pk.w = (unsigned short)bfr(v[3]);
        *(ushort4*)(xlb + (size_t)node * 64 + t * 16 + lg * 4) = pk;
        const f32x4 ws = *(const f32x4*)(attS + t * 16 + lg * 4);
        const f32x4 wd = *(const f32x4*)(attD + t * 16 + lg * 4);
        float p1 = v[0]*ws[0] + v[1]*ws[1] + v[2]*ws[2] + v[3]*ws[3];
        float p2 = v[0]*wd[0] + v[1]*wd[1] + v[2]*wd[2] + v[3]*wd[3];
        p1 += __shfl_xor(p1, 16); p2 += __shfl_xor(p2, 16);
        p1 += __shfl_xor(p1, 32); p2 += __shfl_xor(p2, 32);
        if (lg == 0) {
            asrc[(size_t)node * 4 + t] = p1;
            adst[(size_t)node * 4 + t] = p2;
        }
    }
}

// ---------------- fused GAT softmax + aggregation: one wave per node, bf16 xl ----------------
__global__ __launch_bounds__(256) void gat_node_kernel(
    const int* __restrict__ cnt, const int* __restrict__ eid,
    const int* __restrict__ src_idx,
    const float* __restrict__ asrc, const float* __restrict__ adst,
    const unsigned short* __restrict__ xlb, const float* __restrict__ bias,
    float* __restrict__ out, int N)
{
    const int wid = (blockIdx.x * blockDim.x + threadIdx.x) >> 6;
    const int lane = threadIdx.x & 63;
    if (wid >= N) return;
    const int n = wid;
    const int m = min(cnt[n], CAP);
    const int h = lane >> 4, c16 = lane & 15;
    const int nslot = (m + 15) >> 4;             // <= 8
    const float ad = adst[n * 4 + h];
    float aself = asrc[n * 4 + h] + ad;
    aself = aself > 0.f ? aself : 0.2f * aself;
    const int* el = eid + (size_t)n * CAP;
    int   ss[8];
    float aa[8];
    float mx = aself;
    #pragma unroll
    for (int k = 0; k < 8; ++k) {
        if (k >= nslot) break;
        int i = k * 16 + c16;
        if (i < m) {
            int s = src_idx[el[i]];
            float a = asrc[s * 4 + h] + ad;
            a = a > 0.f ? a : 0.2f * a;
            ss[k] = s; aa[k] = a;
            mx = fmaxf(mx, a);
        } else { ss[k] = 0; aa[k] = -1e30f; }
    }
    #pragma unroll
    for (int off = 1; off < 16; off <<= 1) mx = fmaxf(mx, __shfl_xor(mx, off));
    float ea[8];
    float p = 0.f;
    #pragma unroll
    for (int k = 0; k < 8; ++k) {
        if (k >= nslot) break;
        ea[k] = __expf(aa[k] - mx);
        p += ea[k];
    }
    #pragma unroll
    for (int off = 1; off < 16; off <<= 1) p += __shfl_xor(p, off);
    float eself = __expf(aself - mx);
    float sacc = eself + p;
    float oacc = eself * bf2f(xlb[(size_t)n * 64 + lane]);
    const int grp = lane & 48;
    #pragma unroll
    for (int k = 0; k < 8; ++k) {
        if (k >= nslot) break;
        const int lim = min(16, m - k * 16);
        #pragma unroll 4
        for (int cc = 0; cc < lim; ++cc) {
            int srcl = grp | cc;
            float w = __shfl(ea[k], srcl);
            int   s = __shfl(ss[k], srcl);
            oacc += w * bf2f(xlb[(size_t)s * 64 + lane]);
        }
    }
    float r = oacc / sacc;
    r += __shfl_xor(r, 16);                      // head mean
    r += __shfl_xor(r, 32);
    if (lane < 16) out[(size_t)n * 16 + lane] = 0.25f * r + bias[lane];
}

extern "C" void kernel_launch(void* const* d_in, const int* in_sizes, int n_in,
                              void* d_out, int out_size, void* d_ws, size_t ws_size,
                              hipStream_t stream)
{
    const float* x     = (const float*)d_in[0];
    const int*   ei    = (const int*)  d_in[1];
    const float* eattr = (const float*)d_in[2];
    const float* hn_h  = (const float*)d_in[3];
    const float* hn_c  = (const float*)d_in[4];
    const float* he_h  = (const float*)d_in[5];
    const float* he_c  = (const float*)d_in[6];
    const float* Wih_n = (const float*)d_in[7];
    const float* Whh_n = (const float*)d_in[8];
    const float* bih_n = (const float*)d_in[9];
    const float* bhh_n = (const float*)d_in[10];
    const float* Wih_e = (const float*)d_in[11];
    const float* Whh_e = (const float*)d_in[12];
    const float* bih_e = (const float*)d_in[13];
    const float* bhh_e = (const float*)d_in[14];
    const float* W_gat = (const float*)d_in[15];
    const float* attS  = (const float*)d_in[16];
    const float* attD  = (const float*)d_in[17];
    const float* biasG = (const float*)d_in[18];

    const int N = in_sizes[0] / 5;
    const int E = in_sizes[2] / 2;

    float* out = (float*)d_out;
    float* hn  = out + (size_t)N * 16;
    float* cn  = hn  + (size_t)N * 128;
    float* he  = cn  + (size_t)N * 128;
    float* ce  = he  + (size_t)E * 32;

    char* p = (char*)d_ws;
    size_t off = 0;
    auto take = [&](size_t bytes) -> void* {
        void* r = p + off;
        off = (off + bytes + 255) & ~(size_t)255;
        return r;
    };
    int*   cnt  = (int*)  take((size_t)N * 4);
    int*   eid  = (int*)  take((size_t)N * CAP * 4);
    unsigned short* xlb = (unsigned short*)take((size_t)N * 64 * 2);
    float* asrc = (float*)take((size_t)N * 4 * 4);
    float* adst = (float*)take((size_t)N * 4 * 4);
    unsigned short* WnF = (unsigned short*)take(512 * 160 * 2);
    unsigned short* WeF = (unsigned short*)take(128 * 64 * 2);
    unsigned short* WgF = (unsigned short*)take(64 * 160 * 2);
    float* bsn = (float*)take(512 * 4);
    float* bse = (float*)take(128 * 4);

    convert_kernel<<<(512 * 160 + 255) / 256, 256, 0, stream>>>(
        Whh_n, Wih_n, bih_n, bhh_n, Whh_e, Wih_e, bih_e, bhh_e, W_gat,
        WnF, WeF, WgF, bsn, bse, cnt, N);
    edge_lstm_mfma<<<(E + 255) / 256, 256, 0, stream>>>(
        eattr, he_h, he_c, WeF, bse, ei + E, cnt, eid, he, ce, E);
    node_lstm_mfma<<<(N + 63) / 64, 256, 0, stream>>>(
        x, hn_h, hn_c, WnF, bsn, hn, cn, N);
    enc_gatxl_kernel<<<(N + 63) / 64, 256, 0, stream>>>(
        cnt, eid, he, hn, WgF, attS, attD, xlb, asrc, adst, N);
    gat_node_kernel<<<(N + 3) / 4, 256, 0, stream>>>(
        cnt, eid, ei, asrc, adst, xlb, biasG, out, N);
}